// Round 1
// baseline (1340.720 us; speedup 1.0000x reference)
//
#include <hip/hip_runtime.h>
#include <hip/hip_bf16.h>

#define NN   20000
#define EE   320000
#define EN   340000   // EE + NN (self loops)
#define HH   8
#define CC   56
#define HC   448
#define SS   896      // fused xl|xr stride
#define DEA  5
#define DINN 32
#define GG   32
#define NEG  0.2f

typedef short bf16x8 __attribute__((ext_vector_type(8)));
typedef float f32x4  __attribute__((ext_vector_type(4)));

static __device__ __forceinline__ unsigned short f2bf(float f) {
  unsigned int u = __float_as_uint(f);
  u += 0x7fffu + ((u >> 16) & 1u);   // round-to-nearest-even
  return (unsigned short)(u >> 16);
}

__global__ void k_zero(float* p, int n) {
  int i = blockIdx.x * 256 + threadIdx.x;
  if (i < n) p[i] = 0.f;
}

__global__ void k_deg_esum(const int* __restrict__ dst, const float* __restrict__ ea,
                           int* deg, float* esum) {
  int e = blockIdx.x * 256 + threadIdx.x;
  if (e >= EE) return;
  int d = dst[e];
  atomicAdd(&deg[d], 1);
  #pragma unroll
  for (int j = 0; j < DEA; j++) atomicAdd(&esum[d * DEA + j], ea[e * DEA + j]);
}

// in-place: esum -> loop_attr = esum / max(deg,1)
__global__ void k_loop_attr(const int* __restrict__ deg, float* esum) {
  int n = blockIdx.x * 256 + threadIdx.x;
  if (n >= NN) return;
  float inv = 1.f / fmaxf((float)deg[n], 1.f);
  #pragma unroll
  for (int j = 0; j < DEA; j++) esum[n * DEA + j] *= inv;
}

// exclusive scan of (deg[n]+1) -> offs[0..NN], single block of 1024
__global__ __launch_bounds__(1024) void k_scan(const int* __restrict__ deg, int* offs) {
  __shared__ int buf[1024];
  __shared__ int carry;
  if (threadIdx.x == 0) carry = 0;
  __syncthreads();
  for (int base = 0; base < NN; base += 1024) {
    int i = base + threadIdx.x;
    int v = (i < NN) ? (deg[i] + 1) : 0;
    buf[threadIdx.x] = v;
    __syncthreads();
    for (int o = 1; o < 1024; o <<= 1) {
      int t = (threadIdx.x >= (unsigned)o) ? buf[threadIdx.x - o] : 0;
      __syncthreads();
      buf[threadIdx.x] += t;
      __syncthreads();
    }
    if (i < NN) offs[i] = carry + buf[threadIdx.x] - v;  // exclusive
    __syncthreads();
    if (threadIdx.x == 1023) carry += buf[1023];
    __syncthreads();
  }
  if (threadIdx.x == 0) offs[NN] = carry;   // == EN
}

__global__ void k_icopy(const int* a, int* b, int n) {
  int i = blockIdx.x * 256 + threadIdx.x;
  if (i < n) b[i] = a[i];
}

__global__ void k_scatter(const int* __restrict__ src, const int* __restrict__ dst,
                          const float* __restrict__ ea, const float* __restrict__ loop_ea,
                          int* cursor, int* __restrict__ csr_src, float* __restrict__ csr_ea) {
  int i = blockIdx.x * 256 + threadIdx.x;
  if (i >= EN) return;
  int s, d; const float* eap;
  if (i < EE) { d = dst[i]; s = src[i]; eap = ea + (size_t)i * DEA; }
  else        { d = i - EE; s = d;      eap = loop_ea + (size_t)d * DEA; }
  int pos = atomicAdd(&cursor[d], 1);
  csr_src[pos] = s;
  float* o = csr_ea + (size_t)pos * DEA;
  #pragma unroll
  for (int j = 0; j < DEA; j++) o[j] = eap[j];
}

// xlr[n, 0:448] = x @ Wl1 ; xlr[n, 448:896] = x @ Wr1   (K = 32)
__global__ __launch_bounds__(256) void k_gemm1(const float* __restrict__ x,
                                               const float* __restrict__ Wl,
                                               const float* __restrict__ Wr,
                                               float* __restrict__ out) {
  int n = blockIdx.x;
  __shared__ float xs[DINN];
  if (threadIdx.x < DINN) xs[threadIdx.x] = x[n * DINN + threadIdx.x];
  __syncthreads();
  for (int col = threadIdx.x; col < SS; col += 256) {
    const float* W = (col < HC) ? (Wl + col) : (Wr + (col - HC));
    float acc = 0.f;
    #pragma unroll
    for (int k = 0; k < DINN; k++) acc += xs[k] * W[k * HC];
    out[(size_t)n * SS + col] = acc;
  }
}

// Fused GATv2 edge attention + online segment-softmax + aggregation.
// One wave per (node, head); lanes = channels (56 active of 64).
__global__ __launch_bounds__(256) void k_attn(
    const float* __restrict__ xl, const float* __restrict__ xr,
    const int* __restrict__ offs, const int* __restrict__ csr_src,
    const float* __restrict__ csr_ea,
    const float* __restrict__ We, const float* __restrict__ att,
    const float* __restrict__ bias, float* __restrict__ out, int apply_elu) {
  int wid = (blockIdx.x << 2) + (threadIdx.x >> 6);
  int n = wid >> 3;
  if (n >= NN) return;
  int h = wid & 7;
  int lane = threadIdx.x & 63;
  bool valid = lane < CC;
  int col = h * CC + (valid ? lane : 0);
  float xr_v  = valid ? xr[(size_t)n * SS + col] : 0.f;
  float att_v = valid ? att[col] : 0.f;
  float w0 = We[0 * HC + col], w1 = We[1 * HC + col], w2 = We[2 * HC + col],
        w3 = We[3 * HC + col], w4 = We[4 * HC + col];
  int e0 = offs[n], e1 = offs[n + 1];
  float m = -3.4e38f, l = 0.f, acc = 0.f;
  for (int e = e0; e < e1; e++) {
    int s = csr_src[e];
    const float* eap = csr_ea + (size_t)e * DEA;
    float ee = eap[0] * w0 + eap[1] * w1 + eap[2] * w2 + eap[3] * w3 + eap[4] * w4;
    float xlv = valid ? xl[(size_t)s * SS + col] : 0.f;
    float t = xlv + xr_v + ee;
    t = t > 0.f ? t : NEG * t;
    float p = valid ? t * att_v : 0.f;
    #pragma unroll
    for (int mm = 32; mm >= 1; mm >>= 1) p += __shfl_xor(p, mm, 64);
    float score = p;
    float mn = fmaxf(m, score);
    float rs = __expf(m - mn);       // first iter: exp(-inf) = 0
    float wv = __expf(score - mn);
    acc = acc * rs + wv * xlv;
    l   = l * rs + wv;
    m = mn;
  }
  if (valid) {
    float o = acc / (l + 1e-16f) + bias[col];
    if (apply_elu) o = o > 0.f ? o : (__expf(o) - 1.f);
    out[(size_t)n * HC + col] = o;
  }
}

// per-channel sum / sumsq over NN rows (448-thread blocks, coalesced rows)
__global__ __launch_bounds__(448) void k_bnstats(const float* __restrict__ h, float* stat) {
  int c = threadIdx.x;
  float s = 0.f, sq = 0.f;
  for (int r = blockIdx.x; r < NN; r += gridDim.x) {
    float v = h[(size_t)r * HC + c];
    s += v; sq += v * v;
  }
  atomicAdd(&stat[c], s);
  atomicAdd(&stat[HC + c], sq);
}

__global__ __launch_bounds__(448) void k_bnfinal(float* stat, const float* __restrict__ gam,
                                                 const float* __restrict__ bet) {
  int c = threadIdx.x;
  float mean = stat[c] * (1.f / NN);
  float var  = stat[HC + c] * (1.f / NN) - mean * mean;
  float sc = rsqrtf(var + 1e-5f) * gam[c];
  stat[2 * HC + c] = sc;
  stat[3 * HC + c] = bet[c] - mean * sc;
}

__global__ void k_bnapply(const float* __restrict__ h, const float* __restrict__ stat,
                          unsigned short* __restrict__ hA) {
  int i = blockIdx.x * 256 + threadIdx.x;
  if (i >= NN * HC) return;
  int c = i % HC;
  hA[i] = f2bf(h[i] * stat[2 * HC + c] + stat[3 * HC + c]);
}

// W2t[nn][k] = (nn<448 ? Wl2 : Wr2)[k][nn mod 448], cast to bf16
__global__ void k_w2t(const float* __restrict__ Wl2, const float* __restrict__ Wr2,
                      unsigned short* __restrict__ Bt) {
  int i = blockIdx.x * 256 + threadIdx.x;
  if (i >= SS * HC) return;
  int nn = i / HC, k = i - nn * HC;
  float v = (nn < HC) ? Wl2[k * HC + nn] : Wr2[k * HC + (nn - HC)];
  Bt[nn * HC + k] = f2bf(v);
}

// bf16 MFMA GEMM: out[M=NN, N=896] = A[M,448] * Bt[896,448]^T  (fp32 out)
__global__ __launch_bounds__(256) void k_gemm2(const unsigned short* __restrict__ A,
                                               const unsigned short* __restrict__ Bt,
                                               float* __restrict__ out) {
  int w = threadIdx.x >> 6;
  int lane = threadIdx.x & 63;
  int q = lane >> 4, r = lane & 15;
  int m_base = blockIdx.x * 64 + w * 16;
  int n_base = blockIdx.y * 64;
  f32x4 zero = {0.f, 0.f, 0.f, 0.f};
  f32x4 acc[4] = {zero, zero, zero, zero};
  int arow = m_base + r;
  if (arow >= NN) arow = NN - 1;           // clamp loads, guard stores
  const unsigned short* Ap = A + (size_t)arow * HC + q * 8;
  const unsigned short* Bp0 = Bt + (size_t)(n_base + r) * HC + q * 8;
  for (int k0 = 0; k0 < HC; k0 += 32) {
    bf16x8 a = *(const bf16x8*)(Ap + k0);
    #pragma unroll
    for (int j = 0; j < 4; j++) {
      bf16x8 b = *(const bf16x8*)(Bp0 + (size_t)j * 16 * HC + k0);
      acc[j] = __builtin_amdgcn_mfma_f32_16x16x32_bf16(a, b, acc[j], 0, 0, 0);
    }
  }
  #pragma unroll
  for (int j = 0; j < 4; j++) {
    #pragma unroll
    for (int i = 0; i < 4; i++) {
      int row = m_base + q * 4 + i;        // C/D: col=lane&15, row=(lane>>4)*4+reg
      if (row < NN) out[(size_t)row * SS + n_base + j * 16 + r] = acc[j][i];
    }
  }
}

__global__ void k_cnt(const int* __restrict__ batch, int* cnt) {
  int i = blockIdx.x * 256 + threadIdx.x;
  if (i < NN) atomicAdd(&cnt[batch[i]], 1);
}

// segment-sum pool over sorted batch; 448-thread blocks, running local sum
__global__ __launch_bounds__(448) void k_pool(const float* __restrict__ h2,
                                              const int* __restrict__ batch,
                                              float* pooled) {
  int c = threadIdx.x;
  int rows_per = (NN + gridDim.x - 1) / gridDim.x;
  int r0 = blockIdx.x * rows_per, r1 = min(NN, r0 + rows_per);
  if (r0 >= r1) return;
  float loc = 0.f;
  int gcur = batch[r0];
  for (int r = r0; r < r1; r++) {
    int g = batch[r];
    if (g != gcur) { atomicAdd(&pooled[gcur * HC + c], loc); loc = 0.f; gcur = g; }
    loc += h2[(size_t)r * HC + c];
  }
  atomicAdd(&pooled[gcur * HC + c], loc);
}

// pooled mean -> BN over 32 graphs -> logits -> log_softmax (single block)
__global__ __launch_bounds__(448) void k_final(const float* __restrict__ pooled_sum,
                                               const int* __restrict__ cnt,
                                               const float* __restrict__ gam,
                                               const float* __restrict__ bet,
                                               const float* __restrict__ Wlin,
                                               const float* __restrict__ blin,
                                               float* __restrict__ out) {
  __shared__ float P[GG * HC];
  __shared__ float L[GG * 18];
  __shared__ float red[GG];
  int c = threadIdx.x;
  float s = 0.f, sq = 0.f;
  for (int g = 0; g < GG; g++) {
    float v = pooled_sum[g * HC + c] / fmaxf((float)cnt[g], 1.f);
    P[g * HC + c] = v; s += v; sq += v * v;
  }
  float mean = s * (1.f / GG);
  float var  = sq * (1.f / GG) - mean * mean;
  float sc = rsqrtf(var + 1e-5f) * gam[c];
  float sh = bet[c] - mean * sc;
  for (int g = 0; g < GG; g++) P[g * HC + c] = P[g * HC + c] * sc + sh;
  __syncthreads();
  for (int o = c; o < GG * 18; o += HC) {
    int g = o / 18, j = o - g * 18;
    float acc = blin[j];
    for (int k = 0; k < HC; k++) acc += P[g * HC + k] * Wlin[k * 18 + j];
    L[o] = acc;
  }
  __syncthreads();
  if (c < GG) {
    float mx = -3.4e38f;
    for (int j = 0; j < 18; j++) mx = fmaxf(mx, L[c * 18 + j]);
    float se = 0.f;
    for (int j = 0; j < 18; j++) se += __expf(L[c * 18 + j] - mx);
    red[c] = mx + logf(se);
  }
  __syncthreads();
  for (int o = c; o < GG * 18; o += HC) out[o] = L[o] - red[o / 18];
}

extern "C" void kernel_launch(void* const* d_in, const int* in_sizes, int n_in,
                              void* d_out, int out_size, void* d_ws, size_t ws_size,
                              hipStream_t stream) {
  (void)in_sizes; (void)n_in; (void)out_size; (void)ws_size;
  const float* x     = (const float*)d_in[0];
  const int*   ei    = (const int*)d_in[1];
  const float* ea    = (const float*)d_in[2];
  const int*   batch = (const int*)d_in[3];
  const float* Wl1   = (const float*)d_in[4];
  const float* Wr1   = (const float*)d_in[5];
  const float* We1   = (const float*)d_in[6];
  const float* att1  = (const float*)d_in[7];
  const float* bias1 = (const float*)d_in[8];
  const float* Wl2   = (const float*)d_in[9];
  const float* Wr2   = (const float*)d_in[10];
  const float* We2   = (const float*)d_in[11];
  const float* att2  = (const float*)d_in[12];
  const float* bias2 = (const float*)d_in[13];
  const float* gam   = (const float*)d_in[14];
  const float* bet   = (const float*)d_in[15];
  const float* Wlin  = (const float*)d_in[16];
  const float* blin  = (const float*)d_in[17];
  float* out = (float*)d_out;
  const int* srcp = ei;
  const int* dstp = ei + EE;

  char* ws = (char*)d_ws;
  size_t off = 0;
  auto alloc = [&](size_t bytes) -> char* {
    char* p = ws + off;
    off = (off + bytes + 255) & ~(size_t)255;
    return p;
  };
  int*   offs    = (int*)  alloc((NN + 1) * 4);
  int*   cursor  = (int*)  alloc(NN * 4);
  int*   deg     = (int*)  alloc(NN * 4);
  float* esum    = (float*)alloc(NN * DEA * 4);
  int*   csr_src = (int*)  alloc((size_t)EN * 4);
  float* csr_ea  = (float*)alloc((size_t)EN * DEA * 4);
  float* xlr     = (float*)alloc((size_t)NN * SS * 4);   // layer1 xl|xr, reused for layer2
  float* h1      = (float*)alloc((size_t)NN * HC * 4);   // layer1 out (elu), reused as layer2 out
  unsigned short* h1A = (unsigned short*)alloc((size_t)NN * HC * 2);
  unsigned short* W2t = (unsigned short*)alloc((size_t)SS * HC * 2);
  float* bnstat  = (float*)alloc(HC * 4 * 4);
  float* pooled  = (float*)alloc(GG * HC * 4);
  int*   cnt     = (int*)  alloc(GG * 4);

  // ---- preprocessing: self-loop attrs + CSR by dst ----
  k_zero<<<(NN + 255) / 256, 256, 0, stream>>>((float*)deg, NN);
  k_zero<<<(NN * DEA + 255) / 256, 256, 0, stream>>>(esum, NN * DEA);
  k_deg_esum<<<(EE + 255) / 256, 256, 0, stream>>>(dstp, ea, deg, esum);
  k_loop_attr<<<(NN + 255) / 256, 256, 0, stream>>>(deg, esum);
  k_scan<<<1, 1024, 0, stream>>>(deg, offs);
  k_icopy<<<(NN + 255) / 256, 256, 0, stream>>>(offs, cursor, NN);
  k_scatter<<<(EN + 255) / 256, 256, 0, stream>>>(srcp, dstp, ea, esum, cursor, csr_src, csr_ea);

  // ---- layer 1 ----
  k_gemm1<<<NN, 256, 0, stream>>>(x, Wl1, Wr1, xlr);
  k_attn<<<NN * HH / 4, 256, 0, stream>>>(xlr, xlr + HC, offs, csr_src, csr_ea,
                                          We1, att1, bias1, h1, 1);
  // ---- BN ----
  k_zero<<<(2 * HC + 255) / 256, 256, 0, stream>>>(bnstat, 2 * HC);
  k_bnstats<<<256, HC, 0, stream>>>(h1, bnstat);
  k_bnfinal<<<1, HC, 0, stream>>>(bnstat, gam, bet);
  k_bnapply<<<(NN * HC + 255) / 256, 256, 0, stream>>>(h1, bnstat, h1A);

  // ---- layer 2 ----
  k_w2t<<<(SS * HC + 255) / 256, 256, 0, stream>>>(Wl2, Wr2, W2t);
  dim3 g2((NN + 63) / 64, SS / 64);
  k_gemm2<<<g2, 256, 0, stream>>>(h1A, W2t, xlr);
  k_attn<<<NN * HH / 4, 256, 0, stream>>>(xlr, xlr + HC, offs, csr_src, csr_ea,
                                          We2, att2, bias2, h1, 0);

  // ---- pool + final ----
  k_zero<<<(GG * HC + 255) / 256, 256, 0, stream>>>(pooled, GG * HC);
  k_zero<<<1, 256, 0, stream>>>((float*)cnt, GG);
  k_cnt<<<(NN + 255) / 256, 256, 0, stream>>>(batch, cnt);
  k_pool<<<160, HC, 0, stream>>>(h1, batch, pooled);
  k_final<<<1, HC, 0, stream>>>(pooled, cnt, gam, bet, Wlin, blin, out);
}

// Round 2
// 977.623 us; speedup vs baseline: 1.3714x; 1.3714x over previous
//
#include <hip/hip_runtime.h>
#include <hip/hip_bf16.h>

#define NN   20000
#define EE   320000
#define EN   340000   // EE + NN (self loops)
#define HH   8
#define CC   56
#define HC   448
#define SS   896      // fused xl|xr stride
#define DEA  5
#define EAS  8        // padded csr_ea stride (floats)
#define DINN 32
#define GG   32
#define NEG  0.2f

typedef short bf16x8 __attribute__((ext_vector_type(8)));
typedef float f32x4  __attribute__((ext_vector_type(4)));

static __device__ __forceinline__ unsigned short f2bf(float f) {
  unsigned int u = __float_as_uint(f);
  u += 0x7fffu + ((u >> 16) & 1u);   // round-to-nearest-even
  return (unsigned short)(u >> 16);
}

__global__ void k_zero(float* p, int n) {
  int i = blockIdx.x * 256 + threadIdx.x;
  if (i < n) p[i] = 0.f;
}

__global__ void k_deg_esum(const int* __restrict__ dst, const float* __restrict__ ea,
                           int* deg, float* esum) {
  int e = blockIdx.x * 256 + threadIdx.x;
  if (e >= EE) return;
  int d = dst[e];
  atomicAdd(&deg[d], 1);
  #pragma unroll
  for (int j = 0; j < DEA; j++) atomicAdd(&esum[d * DEA + j], ea[e * DEA + j]);
}

// in-place: esum -> loop_attr = esum / max(deg,1)
__global__ void k_loop_attr(const int* __restrict__ deg, float* esum) {
  int n = blockIdx.x * 256 + threadIdx.x;
  if (n >= NN) return;
  float inv = 1.f / fmaxf((float)deg[n], 1.f);
  #pragma unroll
  for (int j = 0; j < DEA; j++) esum[n * DEA + j] *= inv;
}

// exclusive scan of (deg[n]+1) -> offs[0..NN]; 1024 threads x 20 serial elems
__global__ __launch_bounds__(1024) void k_scan(const int* __restrict__ deg, int* offs) {
  __shared__ int tot[1024];
  int t = threadIdx.x;
  int base = t * 20;
  int loc[20];
  int s = 0;
  #pragma unroll
  for (int i = 0; i < 20; i++) {
    int idx = base + i;
    int v = (idx < NN) ? deg[idx] + 1 : 0;
    loc[i] = s;           // thread-local exclusive prefix
    s += v;
  }
  tot[t] = s;
  __syncthreads();
  for (int o = 1; o < 1024; o <<= 1) {
    int v = (t >= o) ? tot[t - o] : 0;
    __syncthreads();
    tot[t] += v;
    __syncthreads();
  }
  int basesum = (t == 0) ? 0 : tot[t - 1];
  #pragma unroll
  for (int i = 0; i < 20; i++) {
    int idx = base + i;
    if (idx < NN) offs[idx] = basesum + loc[i];
  }
  if (t == 1023) offs[NN] = tot[1023];
}

__global__ void k_icopy(const int* a, int* b, int n) {
  int i = blockIdx.x * 256 + threadIdx.x;
  if (i < n) b[i] = a[i];
}

__global__ void k_scatter(const int* __restrict__ src, const int* __restrict__ dst,
                          const float* __restrict__ ea, const float* __restrict__ loop_ea,
                          int* cursor, int* __restrict__ csr_src, float* __restrict__ csr_ea) {
  int i = blockIdx.x * 256 + threadIdx.x;
  if (i >= EN) return;
  int s, d; const float* eap;
  if (i < EE) { d = dst[i]; s = src[i]; eap = ea + (size_t)i * DEA; }
  else        { d = i - EE; s = d;      eap = loop_ea + (size_t)d * DEA; }
  int pos = atomicAdd(&cursor[d], 1);
  csr_src[pos] = s;
  float* o = csr_ea + (size_t)pos * EAS;
  #pragma unroll
  for (int j = 0; j < DEA; j++) o[j] = eap[j];
}

// xlr[n, 0:448] = x @ Wl1 ; xlr[n, 448:896] = x @ Wr1   (K = 32), 16 rows/block
__global__ __launch_bounds__(256) void k_gemm1(const float* __restrict__ x,
                                               const float* __restrict__ Wl,
                                               const float* __restrict__ Wr,
                                               float* __restrict__ out) {
  int n0 = blockIdx.x * 16;
  __shared__ float xs[16][DINN];
  int t = threadIdx.x;
  for (int i = t; i < 16 * DINN; i += 256) {
    int r = i >> 5, k = i & 31;
    int row = n0 + r;
    xs[r][k] = (row < NN) ? x[(size_t)row * DINN + k] : 0.f;
  }
  __syncthreads();
  for (int col = t; col < SS; col += 256) {
    const float* W = (col < HC) ? (Wl + col) : (Wr + (col - HC));
    float acc[16];
    #pragma unroll
    for (int r = 0; r < 16; r++) acc[r] = 0.f;
    for (int k = 0; k < DINN; k++) {
      float wk = W[k * HC];
      #pragma unroll
      for (int r = 0; r < 16; r++) acc[r] += xs[r][k] * wk;
    }
    #pragma unroll
    for (int r = 0; r < 16; r++) {
      int row = n0 + r;
      if (row < NN) out[(size_t)row * SS + col] = acc[r];
    }
  }
}

// Fused GATv2 attention v2: wave = one (node, head); 4 edge-groups x 16 lanes,
// lane covers 4 channels (float4). Max-free softmax (scores bounded; clamp 60).
__global__ __launch_bounds__(256) void k_attn(
    const float* __restrict__ xlr_base,
    const int* __restrict__ offs, const int* __restrict__ csr_src,
    const float* __restrict__ csr_ea,
    const float* __restrict__ We, const float* __restrict__ att,
    const float* __restrict__ bias, float* __restrict__ out, int apply_elu) {
  int wid = (blockIdx.x << 2) + (threadIdx.x >> 6);
  int n = wid >> 3;
  if (n >= NN) return;
  int h = wid & 7;
  int lane = threadIdx.x & 63;
  int grp  = lane >> 4;          // which edge in the 4-wide batch
  int gl   = lane & 15;          // lane within group
  bool cvalid = gl < 14;         // 14 lanes x 4ch = 56 channels
  int cj = cvalid ? gl : 13;     // clamp for safe loads
  int colbase = h * CC + cj * 4;

  f32x4 xr4  = *(const f32x4*)(xlr_base + (size_t)n * SS + HC + colbase);
  f32x4 att4 = *(const f32x4*)(att + colbase);
  if (!cvalid) att4 = (f32x4){0.f, 0.f, 0.f, 0.f};
  f32x4 w0 = *(const f32x4*)(We + 0 * HC + colbase);
  f32x4 w1 = *(const f32x4*)(We + 1 * HC + colbase);
  f32x4 w2 = *(const f32x4*)(We + 2 * HC + colbase);
  f32x4 w3 = *(const f32x4*)(We + 3 * HC + colbase);
  f32x4 w4 = *(const f32x4*)(We + 4 * HC + colbase);

  int e0 = offs[n], e1 = offs[n + 1];
  float l = 0.f;
  f32x4 acc = {0.f, 0.f, 0.f, 0.f};

  for (int e = e0 + grp; e < e1; e += 4) {
    int s = csr_src[e];
    const float* eap = csr_ea + (size_t)e * EAS;
    f32x4 ea01 = *(const f32x4*)eap;       // attrs 0..3
    float ea4  = eap[4];
    f32x4 xl4 = *(const f32x4*)(xlr_base + (size_t)s * SS + colbase);
    f32x4 t = xl4 + xr4;
    t += ea01.x * w0; t += ea01.y * w1; t += ea01.z * w2; t += ea01.w * w3;
    t += ea4 * w4;
    // leaky relu: max(t, 0.2t)
    t.x = fmaxf(t.x, NEG * t.x); t.y = fmaxf(t.y, NEG * t.y);
    t.z = fmaxf(t.z, NEG * t.z); t.w = fmaxf(t.w, NEG * t.w);
    float p = t.x * att4.x + t.y * att4.y + t.z * att4.z + t.w * att4.w;
    p += __shfl_xor(p, 1, 64);
    p += __shfl_xor(p, 2, 64);
    p += __shfl_xor(p, 4, 64);
    p += __shfl_xor(p, 8, 64);
    float wv = __expf(fminf(p, 60.f));
    acc += wv * xl4;
    l += wv;
  }
  // merge 4 groups (butterfly over xor 16, 32)
  l += __shfl_xor(l, 16, 64);
  l += __shfl_xor(l, 32, 64);
  acc.x += __shfl_xor(acc.x, 16, 64); acc.x += __shfl_xor(acc.x, 32, 64);
  acc.y += __shfl_xor(acc.y, 16, 64); acc.y += __shfl_xor(acc.y, 32, 64);
  acc.z += __shfl_xor(acc.z, 16, 64); acc.z += __shfl_xor(acc.z, 32, 64);
  acc.w += __shfl_xor(acc.w, 16, 64); acc.w += __shfl_xor(acc.w, 32, 64);

  if (lane < 14) {
    f32x4 b4 = *(const f32x4*)(bias + colbase);
    float inv = 1.f / (l + 1e-16f);
    f32x4 o = acc * inv + b4;
    if (apply_elu) {
      o.x = o.x > 0.f ? o.x : (__expf(o.x) - 1.f);
      o.y = o.y > 0.f ? o.y : (__expf(o.y) - 1.f);
      o.z = o.z > 0.f ? o.z : (__expf(o.z) - 1.f);
      o.w = o.w > 0.f ? o.w : (__expf(o.w) - 1.f);
    }
    *(f32x4*)(out + (size_t)n * HC + colbase) = o;
  }
}

// per-channel sum / sumsq over NN rows
__global__ __launch_bounds__(448) void k_bnstats(const float* __restrict__ h, float* stat) {
  int c = threadIdx.x;
  float s = 0.f, sq = 0.f;
  for (int r = blockIdx.x; r < NN; r += gridDim.x) {
    float v = h[(size_t)r * HC + c];
    s += v; sq += v * v;
  }
  atomicAdd(&stat[c], s);
  atomicAdd(&stat[HC + c], sq);
}

__global__ __launch_bounds__(448) void k_bnfinal(float* stat, const float* __restrict__ gam,
                                                 const float* __restrict__ bet) {
  int c = threadIdx.x;
  float mean = stat[c] * (1.f / NN);
  float var  = stat[HC + c] * (1.f / NN) - mean * mean;
  float sc = rsqrtf(var + 1e-5f) * gam[c];
  stat[2 * HC + c] = sc;
  stat[3 * HC + c] = bet[c] - mean * sc;
}

__global__ void k_bnapply(const float* __restrict__ h, const float* __restrict__ stat,
                          unsigned short* __restrict__ hA) {
  int i = blockIdx.x * 256 + threadIdx.x;
  if (i >= NN * HC) return;
  int c = i % HC;
  hA[i] = f2bf(h[i] * stat[2 * HC + c] + stat[3 * HC + c]);
}

// W2t[nn][k] = (nn<448 ? Wl2 : Wr2)[k][nn mod 448], cast to bf16
__global__ void k_w2t(const float* __restrict__ Wl2, const float* __restrict__ Wr2,
                      unsigned short* __restrict__ Bt) {
  int i = blockIdx.x * 256 + threadIdx.x;
  if (i >= SS * HC) return;
  int nn = i / HC, k = i - nn * HC;
  float v = (nn < HC) ? Wl2[k * HC + nn] : Wr2[k * HC + (nn - HC)];
  Bt[nn * HC + k] = f2bf(v);
}

// bf16 MFMA GEMM: out[M=NN, N=896] = A[M,448] * Bt[896,448]^T  (fp32 out)
__global__ __launch_bounds__(256) void k_gemm2(const unsigned short* __restrict__ A,
                                               const unsigned short* __restrict__ Bt,
                                               float* __restrict__ out) {
  int w = threadIdx.x >> 6;
  int lane = threadIdx.x & 63;
  int q = lane >> 4, r = lane & 15;
  int m_base = blockIdx.x * 64 + w * 16;
  int n_base = blockIdx.y * 64;
  f32x4 zero = {0.f, 0.f, 0.f, 0.f};
  f32x4 acc[4] = {zero, zero, zero, zero};
  int arow = m_base + r;
  if (arow >= NN) arow = NN - 1;           // clamp loads, guard stores
  const unsigned short* Ap = A + (size_t)arow * HC + q * 8;
  const unsigned short* Bp0 = Bt + (size_t)(n_base + r) * HC + q * 8;
  for (int k0 = 0; k0 < HC; k0 += 32) {
    bf16x8 a = *(const bf16x8*)(Ap + k0);
    #pragma unroll
    for (int j = 0; j < 4; j++) {
      bf16x8 b = *(const bf16x8*)(Bp0 + (size_t)j * 16 * HC + k0);
      acc[j] = __builtin_amdgcn_mfma_f32_16x16x32_bf16(a, b, acc[j], 0, 0, 0);
    }
  }
  #pragma unroll
  for (int j = 0; j < 4; j++) {
    #pragma unroll
    for (int i = 0; i < 4; i++) {
      int row = m_base + q * 4 + i;        // C/D: col=lane&15, row=(lane>>4)*4+reg
      if (row < NN) out[(size_t)row * SS + n_base + j * 16 + r] = acc[j][i];
    }
  }
}

__global__ void k_cnt(const int* __restrict__ batch, int* cnt) {
  int i = blockIdx.x * 256 + threadIdx.x;
  if (i < NN) atomicAdd(&cnt[batch[i]], 1);
}

// segment-sum pool over sorted batch; running local sum per block chunk
__global__ __launch_bounds__(448) void k_pool(const float* __restrict__ h2,
                                              const int* __restrict__ batch,
                                              float* pooled) {
  int c = threadIdx.x;
  int rows_per = (NN + gridDim.x - 1) / gridDim.x;
  int r0 = blockIdx.x * rows_per, r1 = min(NN, r0 + rows_per);
  if (r0 >= r1) return;
  float loc = 0.f;
  int gcur = batch[r0];
  for (int r = r0; r < r1; r++) {
    int g = batch[r];
    if (g != gcur) { atomicAdd(&pooled[gcur * HC + c], loc); loc = 0.f; gcur = g; }
    loc += h2[(size_t)r * HC + c];
  }
  atomicAdd(&pooled[gcur * HC + c], loc);
}

// pooled mean -> BN over 32 graphs -> logits -> log_softmax (single block)
__global__ __launch_bounds__(448) void k_final(const float* __restrict__ pooled_sum,
                                               const int* __restrict__ cnt,
                                               const float* __restrict__ gam,
                                               const float* __restrict__ bet,
                                               const float* __restrict__ Wlin,
                                               const float* __restrict__ blin,
                                               float* __restrict__ out) {
  __shared__ float P[GG * HC];
  __shared__ float L[GG * 18];
  __shared__ float red[GG];
  int c = threadIdx.x;
  float s = 0.f, sq = 0.f;
  for (int g = 0; g < GG; g++) {
    float v = pooled_sum[g * HC + c] / fmaxf((float)cnt[g], 1.f);
    P[g * HC + c] = v; s += v; sq += v * v;
  }
  float mean = s * (1.f / GG);
  float var  = sq * (1.f / GG) - mean * mean;
  float sc = rsqrtf(var + 1e-5f) * gam[c];
  float sh = bet[c] - mean * sc;
  for (int g = 0; g < GG; g++) P[g * HC + c] = P[g * HC + c] * sc + sh;
  __syncthreads();
  for (int o = c; o < GG * 18; o += HC) {
    int g = o / 18, j = o - g * 18;
    float acc = blin[j];
    for (int k = 0; k < HC; k++) acc += P[g * HC + k] * Wlin[k * 18 + j];
    L[o] = acc;
  }
  __syncthreads();
  if (c < GG) {
    float mx = -3.4e38f;
    for (int j = 0; j < 18; j++) mx = fmaxf(mx, L[c * 18 + j]);
    float se = 0.f;
    for (int j = 0; j < 18; j++) se += __expf(L[c * 18 + j] - mx);
    red[c] = mx + logf(se);
  }
  __syncthreads();
  for (int o = c; o < GG * 18; o += HC) out[o] = L[o] - red[o / 18];
}

extern "C" void kernel_launch(void* const* d_in, const int* in_sizes, int n_in,
                              void* d_out, int out_size, void* d_ws, size_t ws_size,
                              hipStream_t stream) {
  (void)in_sizes; (void)n_in; (void)out_size; (void)ws_size;
  const float* x     = (const float*)d_in[0];
  const int*   ei    = (const int*)d_in[1];
  const float* ea    = (const float*)d_in[2];
  const int*   batch = (const int*)d_in[3];
  const float* Wl1   = (const float*)d_in[4];
  const float* Wr1   = (const float*)d_in[5];
  const float* We1   = (const float*)d_in[6];
  const float* att1  = (const float*)d_in[7];
  const float* bias1 = (const float*)d_in[8];
  const float* Wl2   = (const float*)d_in[9];
  const float* Wr2   = (const float*)d_in[10];
  const float* We2   = (const float*)d_in[11];
  const float* att2  = (const float*)d_in[12];
  const float* bias2 = (const float*)d_in[13];
  const float* gam   = (const float*)d_in[14];
  const float* bet   = (const float*)d_in[15];
  const float* Wlin  = (const float*)d_in[16];
  const float* blin  = (const float*)d_in[17];
  float* out = (float*)d_out;
  const int* srcp = ei;
  const int* dstp = ei + EE;

  char* ws = (char*)d_ws;
  size_t off = 0;
  auto alloc = [&](size_t bytes) -> char* {
    char* p = ws + off;
    off = (off + bytes + 255) & ~(size_t)255;
    return p;
  };
  int*   offs    = (int*)  alloc((NN + 1) * 4);
  int*   cursor  = (int*)  alloc(NN * 4);
  int*   deg     = (int*)  alloc(NN * 4);
  float* esum    = (float*)alloc(NN * DEA * 4);
  int*   csr_src = (int*)  alloc((size_t)EN * 4);
  float* csr_ea  = (float*)alloc((size_t)EN * EAS * 4);
  float* xlr     = (float*)alloc((size_t)NN * SS * 4);   // layer1 xl|xr, reused for layer2
  float* h1      = (float*)alloc((size_t)NN * HC * 4);   // layer1 out (elu), reused as layer2 out
  unsigned short* h1A = (unsigned short*)alloc((size_t)NN * HC * 2);
  unsigned short* W2t = (unsigned short*)alloc((size_t)SS * HC * 2);
  float* bnstat  = (float*)alloc(HC * 4 * 4);
  float* pooled  = (float*)alloc(GG * HC * 4);
  int*   cnt     = (int*)  alloc(GG * 4);

  // ---- preprocessing: self-loop attrs + CSR by dst ----
  k_zero<<<(NN + 255) / 256, 256, 0, stream>>>((float*)deg, NN);
  k_zero<<<(NN * DEA + 255) / 256, 256, 0, stream>>>(esum, NN * DEA);
  k_deg_esum<<<(EE + 255) / 256, 256, 0, stream>>>(dstp, ea, deg, esum);
  k_loop_attr<<<(NN + 255) / 256, 256, 0, stream>>>(deg, esum);
  k_scan<<<1, 1024, 0, stream>>>(deg, offs);
  k_icopy<<<(NN + 255) / 256, 256, 0, stream>>>(offs, cursor, NN);
  k_scatter<<<(EN + 255) / 256, 256, 0, stream>>>(srcp, dstp, ea, esum, cursor, csr_src, csr_ea);

  // ---- layer 1 ----
  k_gemm1<<<(NN + 15) / 16, 256, 0, stream>>>(x, Wl1, Wr1, xlr);
  k_attn<<<NN * HH / 4, 256, 0, stream>>>(xlr, offs, csr_src, csr_ea,
                                          We1, att1, bias1, h1, 1);
  // ---- BN ----
  k_zero<<<(2 * HC + 255) / 256, 256, 0, stream>>>(bnstat, 2 * HC);
  k_bnstats<<<1024, HC, 0, stream>>>(h1, bnstat);
  k_bnfinal<<<1, HC, 0, stream>>>(bnstat, gam, bet);
  k_bnapply<<<(NN * HC + 255) / 256, 256, 0, stream>>>(h1, bnstat, h1A);

  // ---- layer 2 ----
  k_w2t<<<(SS * HC + 255) / 256, 256, 0, stream>>>(Wl2, Wr2, W2t);
  dim3 g2((NN + 63) / 64, SS / 64);
  k_gemm2<<<g2, 256, 0, stream>>>(h1A, W2t, xlr);
  k_attn<<<NN * HH / 4, 256, 0, stream>>>(xlr, offs, csr_src, csr_ea,
                                          We2, att2, bias2, h1, 0);

  // ---- pool + final ----
  k_zero<<<(GG * HC + 255) / 256, 256, 0, stream>>>(pooled, GG * HC);
  k_zero<<<1, 256, 0, stream>>>((float*)cnt, GG);
  k_cnt<<<(NN + 255) / 256, 256, 0, stream>>>(batch, cnt);
  k_pool<<<640, HC, 0, stream>>>(h1, batch, pooled);
  k_final<<<1, HC, 0, stream>>>(pooled, cnt, gam, bet, Wlin, blin, out);
}

// Round 3
// 917.576 us; speedup vs baseline: 1.4612x; 1.0654x over previous
//
#include <hip/hip_runtime.h>
#include <hip/hip_bf16.h>

#define NN   20000
#define EE   320000
#define EN   340000   // EE + NN (self loops)
#define HH   8
#define CC   56
#define HC   448
#define SS   896      // fused xl|xr stride
#define DEA  5
#define EAS  8        // padded csr_ea stride (floats)
#define DINN 32
#define GG   32
#define NEG  0.2f

typedef short bf16x8 __attribute__((ext_vector_type(8)));
typedef float f32x4  __attribute__((ext_vector_type(4)));

static __device__ __forceinline__ unsigned short f2bf(float f) {
  unsigned int u = __float_as_uint(f);
  u += 0x7fffu + ((u >> 16) & 1u);   // round-to-nearest-even
  return (unsigned short)(u >> 16);
}

static __device__ __forceinline__ f32x4 bf4_to_f32x4(uint2 r) {
  f32x4 o;
  o.x = __uint_as_float(r.x << 16);
  o.y = __uint_as_float(r.x & 0xffff0000u);
  o.z = __uint_as_float(r.y << 16);
  o.w = __uint_as_float(r.y & 0xffff0000u);
  return o;
}

__global__ void k_deg_esum(const int* __restrict__ dst, const float* __restrict__ ea,
                           int* deg, float* esum) {
  int e = blockIdx.x * 256 + threadIdx.x;
  if (e >= EE) return;
  int d = dst[e];
  atomicAdd(&deg[d], 1);
  #pragma unroll
  for (int j = 0; j < DEA; j++) atomicAdd(&esum[d * DEA + j], ea[e * DEA + j]);
}

// exclusive scan of (deg[n]+1) -> offs[0..NN] and cursor[0..NN-1]
__global__ __launch_bounds__(1024) void k_scan(const int* __restrict__ deg, int* offs,
                                               int* cursor) {
  __shared__ int tot[1024];
  int t = threadIdx.x;
  int base = t * 20;
  int loc[20];
  int s = 0;
  #pragma unroll
  for (int i = 0; i < 20; i++) {
    int idx = base + i;
    int v = (idx < NN) ? deg[idx] + 1 : 0;
    loc[i] = s;           // thread-local exclusive prefix
    s += v;
  }
  tot[t] = s;
  __syncthreads();
  for (int o = 1; o < 1024; o <<= 1) {
    int v = (t >= o) ? tot[t - o] : 0;
    __syncthreads();
    tot[t] += v;
    __syncthreads();
  }
  int basesum = (t == 0) ? 0 : tot[t - 1];
  #pragma unroll
  for (int i = 0; i < 20; i++) {
    int idx = base + i;
    if (idx < NN) { offs[idx] = basesum + loc[i]; cursor[idx] = basesum + loc[i]; }
  }
  if (t == 1023) offs[NN] = tot[1023];
}

__global__ void k_scatter(const int* __restrict__ src, const int* __restrict__ dst,
                          const float* __restrict__ ea, const float* __restrict__ esum,
                          const int* __restrict__ deg,
                          int* cursor, int* __restrict__ csr_src, float* __restrict__ csr_ea) {
  int i = blockIdx.x * 256 + threadIdx.x;
  if (i >= EN) return;
  int s, d; float a[DEA];
  if (i < EE) {
    d = dst[i]; s = src[i];
    #pragma unroll
    for (int j = 0; j < DEA; j++) a[j] = ea[(size_t)i * DEA + j];
  } else {
    d = i - EE; s = d;
    float inv = 1.f / fmaxf((float)deg[d], 1.f);   // self-loop attr = mean of incoming
    #pragma unroll
    for (int j = 0; j < DEA; j++) a[j] = esum[(size_t)d * DEA + j] * inv;
  }
  int pos = atomicAdd(&cursor[d], 1);
  csr_src[pos] = s;
  float* o = csr_ea + (size_t)pos * EAS;
  #pragma unroll
  for (int j = 0; j < DEA; j++) o[j] = a[j];
}

// xlr[n, 0:448] = x @ Wl1 ; xlr[n, 448:896] = x @ Wr1 (K=32), 16 rows/block, bf16 out
__global__ __launch_bounds__(256) void k_gemm1(const float* __restrict__ x,
                                               const float* __restrict__ Wl,
                                               const float* __restrict__ Wr,
                                               unsigned short* __restrict__ out) {
  int n0 = blockIdx.x * 16;
  __shared__ float xs[16][DINN];
  int t = threadIdx.x;
  for (int i = t; i < 16 * DINN; i += 256) {
    int r = i >> 5, k = i & 31;
    int row = n0 + r;
    xs[r][k] = (row < NN) ? x[(size_t)row * DINN + k] : 0.f;
  }
  __syncthreads();
  for (int col = t; col < SS; col += 256) {
    const float* W = (col < HC) ? (Wl + col) : (Wr + (col - HC));
    float acc[16];
    #pragma unroll
    for (int r = 0; r < 16; r++) acc[r] = 0.f;
    for (int k = 0; k < DINN; k++) {
      float wk = W[k * HC];
      #pragma unroll
      for (int r = 0; r < 16; r++) acc[r] += xs[r][k] * wk;
    }
    #pragma unroll
    for (int r = 0; r < 16; r++) {
      int row = n0 + r;
      if (row < NN) out[(size_t)row * SS + col] = f2bf(acc[r]);
    }
  }
}

// Fused GATv2 attention v3: wave = (node, head); 4 edge-groups x 16 lanes,
// lane = 4 channels; bf16 xlr gathers; 2x edge unroll (8 gathers in flight).
__global__ __launch_bounds__(256) void k_attn(
    const unsigned short* __restrict__ xlr,
    const int* __restrict__ offs, const int* __restrict__ csr_src,
    const float* __restrict__ csr_ea,
    const float* __restrict__ We, const float* __restrict__ att,
    const float* __restrict__ bias, float* __restrict__ out, int apply_elu) {
  int wid = (blockIdx.x << 2) + (threadIdx.x >> 6);
  int n = wid >> 3;
  if (n >= NN) return;
  int h = wid & 7;
  int lane = threadIdx.x & 63;
  int grp  = lane >> 4;          // which edge in the 4-wide batch
  int gl   = lane & 15;          // lane within group
  bool cvalid = gl < 14;         // 14 lanes x 4ch = 56 channels
  int cj = cvalid ? gl : 13;     // clamp for safe loads
  int colbase = h * CC + cj * 4;

  f32x4 xr4 = bf4_to_f32x4(*(const uint2*)(xlr + (size_t)n * SS + HC + colbase));
  f32x4 att4 = *(const f32x4*)(att + colbase);
  if (!cvalid) att4 = (f32x4){0.f, 0.f, 0.f, 0.f};
  f32x4 w0 = *(const f32x4*)(We + 0 * HC + colbase);
  f32x4 w1 = *(const f32x4*)(We + 1 * HC + colbase);
  f32x4 w2 = *(const f32x4*)(We + 2 * HC + colbase);
  f32x4 w3 = *(const f32x4*)(We + 3 * HC + colbase);
  f32x4 w4 = *(const f32x4*)(We + 4 * HC + colbase);

  int e0 = offs[n], e1 = offs[n + 1];
  float l = 0.f;
  f32x4 acc = {0.f, 0.f, 0.f, 0.f};

  for (int e = e0 + grp; e < e1; e += 8) {
    int eb = e + 4;
    bool h2v = eb < e1;
    int ebc = h2v ? eb : e;
    int s0 = csr_src[e];
    int s1 = csr_src[ebc];
    const float* ep0 = csr_ea + (size_t)e * EAS;
    const float* ep1 = csr_ea + (size_t)ebc * EAS;
    f32x4 ea0 = *(const f32x4*)ep0;  float e40 = ep0[4];
    f32x4 ea1 = *(const f32x4*)ep1;  float e41 = ep1[4];
    uint2 r0 = *(const uint2*)(xlr + (size_t)s0 * SS + colbase);
    uint2 r1 = *(const uint2*)(xlr + (size_t)s1 * SS + colbase);
    f32x4 xl0 = bf4_to_f32x4(r0);
    f32x4 xl1 = bf4_to_f32x4(r1);

    f32x4 t0 = xl0 + xr4;
    t0 += ea0.x * w0; t0 += ea0.y * w1; t0 += ea0.z * w2; t0 += ea0.w * w3; t0 += e40 * w4;
    f32x4 t1 = xl1 + xr4;
    t1 += ea1.x * w0; t1 += ea1.y * w1; t1 += ea1.z * w2; t1 += ea1.w * w3; t1 += e41 * w4;
    t0.x = fmaxf(t0.x, NEG * t0.x); t0.y = fmaxf(t0.y, NEG * t0.y);
    t0.z = fmaxf(t0.z, NEG * t0.z); t0.w = fmaxf(t0.w, NEG * t0.w);
    t1.x = fmaxf(t1.x, NEG * t1.x); t1.y = fmaxf(t1.y, NEG * t1.y);
    t1.z = fmaxf(t1.z, NEG * t1.z); t1.w = fmaxf(t1.w, NEG * t1.w);
    float p0 = t0.x * att4.x + t0.y * att4.y + t0.z * att4.z + t0.w * att4.w;
    float p1 = t1.x * att4.x + t1.y * att4.y + t1.z * att4.z + t1.w * att4.w;
    p0 += __shfl_xor(p0, 1, 64);  p1 += __shfl_xor(p1, 1, 64);
    p0 += __shfl_xor(p0, 2, 64);  p1 += __shfl_xor(p1, 2, 64);
    p0 += __shfl_xor(p0, 4, 64);  p1 += __shfl_xor(p1, 4, 64);
    p0 += __shfl_xor(p0, 8, 64);  p1 += __shfl_xor(p1, 8, 64);
    float wv0 = __expf(fminf(p0, 60.f));
    float wv1 = h2v ? __expf(fminf(p1, 60.f)) : 0.f;
    acc += wv0 * xl0;
    acc += wv1 * xl1;
    l += wv0 + wv1;
  }
  // merge 4 groups (butterfly over xor 16, 32)
  l += __shfl_xor(l, 16, 64);
  l += __shfl_xor(l, 32, 64);
  acc.x += __shfl_xor(acc.x, 16, 64); acc.x += __shfl_xor(acc.x, 32, 64);
  acc.y += __shfl_xor(acc.y, 16, 64); acc.y += __shfl_xor(acc.y, 32, 64);
  acc.z += __shfl_xor(acc.z, 16, 64); acc.z += __shfl_xor(acc.z, 32, 64);
  acc.w += __shfl_xor(acc.w, 16, 64); acc.w += __shfl_xor(acc.w, 32, 64);

  if (lane < 14) {
    f32x4 b4 = *(const f32x4*)(bias + colbase);
    float inv = 1.f / (l + 1e-16f);
    f32x4 o = acc * inv + b4;
    if (apply_elu) {
      o.x = o.x > 0.f ? o.x : (__expf(o.x) - 1.f);
      o.y = o.y > 0.f ? o.y : (__expf(o.y) - 1.f);
      o.z = o.z > 0.f ? o.z : (__expf(o.z) - 1.f);
      o.w = o.w > 0.f ? o.w : (__expf(o.w) - 1.f);
    }
    *(f32x4*)(out + (size_t)n * HC + colbase) = o;
  }
}

// per-channel sum / sumsq over NN rows
__global__ __launch_bounds__(448) void k_bnstats(const float* __restrict__ h, float* stat) {
  int c = threadIdx.x;
  float s = 0.f, sq = 0.f;
  for (int r = blockIdx.x; r < NN; r += gridDim.x) {
    float v = h[(size_t)r * HC + c];
    s += v; sq += v * v;
  }
  atomicAdd(&stat[c], s);
  atomicAdd(&stat[HC + c], sq);
}

// BN finalize folded in: stat holds raw sum / sumsq
__global__ void k_bnapply(const float* __restrict__ h, const float* __restrict__ stat,
                          const float* __restrict__ gam, const float* __restrict__ bet,
                          unsigned short* __restrict__ hA) {
  int i = blockIdx.x * 256 + threadIdx.x;
  if (i >= NN * HC) return;
  int c = i % HC;
  float mean = stat[c] * (1.f / NN);
  float var  = stat[HC + c] * (1.f / NN) - mean * mean;
  float sc = rsqrtf(var + 1e-5f) * gam[c];
  float sh = bet[c] - mean * sc;
  hA[i] = f2bf(h[i] * sc + sh);
}

// W2t[nn][k] = (nn<448 ? Wl2 : Wr2)[k][nn mod 448], cast to bf16
__global__ void k_w2t(const float* __restrict__ Wl2, const float* __restrict__ Wr2,
                      unsigned short* __restrict__ Bt) {
  int i = blockIdx.x * 256 + threadIdx.x;
  if (i >= SS * HC) return;
  int nn = i / HC, k = i - nn * HC;
  float v = (nn < HC) ? Wl2[k * HC + nn] : Wr2[k * HC + (nn - HC)];
  Bt[nn * HC + k] = f2bf(v);
}

// bf16 MFMA GEMM: out[M=NN, N=896] = A[M,448] * Bt[896,448]^T  (bf16 out)
__global__ __launch_bounds__(256) void k_gemm2(const unsigned short* __restrict__ A,
                                               const unsigned short* __restrict__ Bt,
                                               unsigned short* __restrict__ out) {
  int w = threadIdx.x >> 6;
  int lane = threadIdx.x & 63;
  int q = lane >> 4, r = lane & 15;
  int m_base = blockIdx.x * 64 + w * 16;
  int n_base = blockIdx.y * 64;
  f32x4 zero = {0.f, 0.f, 0.f, 0.f};
  f32x4 acc[4] = {zero, zero, zero, zero};
  int arow = m_base + r;
  if (arow >= NN) arow = NN - 1;           // clamp loads, guard stores
  const unsigned short* Ap = A + (size_t)arow * HC + q * 8;
  const unsigned short* Bp0 = Bt + (size_t)(n_base + r) * HC + q * 8;
  for (int k0 = 0; k0 < HC; k0 += 32) {
    bf16x8 a = *(const bf16x8*)(Ap + k0);
    #pragma unroll
    for (int j = 0; j < 4; j++) {
      bf16x8 b = *(const bf16x8*)(Bp0 + (size_t)j * 16 * HC + k0);
      acc[j] = __builtin_amdgcn_mfma_f32_16x16x32_bf16(a, b, acc[j], 0, 0, 0);
    }
  }
  #pragma unroll
  for (int j = 0; j < 4; j++) {
    #pragma unroll
    for (int i = 0; i < 4; i++) {
      int row = m_base + q * 4 + i;        // C/D: col=lane&15, row=(lane>>4)*4+reg
      if (row < NN) out[(size_t)row * SS + n_base + j * 16 + r] = f2bf(acc[j][i]);
    }
  }
}

__global__ void k_cnt(const int* __restrict__ batch, int* cnt) {
  int i = blockIdx.x * 256 + threadIdx.x;
  if (i < NN) atomicAdd(&cnt[batch[i]], 1);
}

// segment-sum pool over sorted batch; running local sum per block chunk
__global__ __launch_bounds__(448) void k_pool(const float* __restrict__ h2,
                                              const int* __restrict__ batch,
                                              float* pooled) {
  int c = threadIdx.x;
  int rows_per = (NN + gridDim.x - 1) / gridDim.x;
  int r0 = blockIdx.x * rows_per, r1 = min(NN, r0 + rows_per);
  if (r0 >= r1) return;
  float loc = 0.f;
  int gcur = batch[r0];
  for (int r = r0; r < r1; r++) {
    int g = batch[r];
    if (g != gcur) { atomicAdd(&pooled[gcur * HC + c], loc); loc = 0.f; gcur = g; }
    loc += h2[(size_t)r * HC + c];
  }
  atomicAdd(&pooled[gcur * HC + c], loc);
}

// pooled mean -> BN over 32 graphs -> logits -> log_softmax (single block)
__global__ __launch_bounds__(448) void k_final(const float* __restrict__ pooled_sum,
                                               const int* __restrict__ cnt,
                                               const float* __restrict__ gam,
                                               const float* __restrict__ bet,
                                               const float* __restrict__ Wlin,
                                               const float* __restrict__ blin,
                                               float* __restrict__ out) {
  __shared__ float P[GG * HC];
  __shared__ float L[GG * 18];
  __shared__ float red[GG];
  int c = threadIdx.x;
  float s = 0.f, sq = 0.f;
  for (int g = 0; g < GG; g++) {
    float v = pooled_sum[g * HC + c] / fmaxf((float)cnt[g], 1.f);
    P[g * HC + c] = v; s += v; sq += v * v;
  }
  float mean = s * (1.f / GG);
  float var  = sq * (1.f / GG) - mean * mean;
  float sc = rsqrtf(var + 1e-5f) * gam[c];
  float sh = bet[c] - mean * sc;
  for (int g = 0; g < GG; g++) P[g * HC + c] = P[g * HC + c] * sc + sh;
  __syncthreads();
  for (int o = c; o < GG * 18; o += HC) {
    int g = o / 18, j = o - g * 18;
    float acc = blin[j];
    for (int k = 0; k < HC; k++) acc += P[g * HC + k] * Wlin[k * 18 + j];
    L[o] = acc;
  }
  __syncthreads();
  if (c < GG) {
    float mx = -3.4e38f;
    for (int j = 0; j < 18; j++) mx = fmaxf(mx, L[c * 18 + j]);
    float se = 0.f;
    for (int j = 0; j < 18; j++) se += __expf(L[c * 18 + j] - mx);
    red[c] = mx + logf(se);
  }
  __syncthreads();
  for (int o = c; o < GG * 18; o += HC) out[o] = L[o] - red[o / 18];
}

extern "C" void kernel_launch(void* const* d_in, const int* in_sizes, int n_in,
                              void* d_out, int out_size, void* d_ws, size_t ws_size,
                              hipStream_t stream) {
  (void)in_sizes; (void)n_in; (void)out_size; (void)ws_size;
  const float* x     = (const float*)d_in[0];
  const int*   ei    = (const int*)d_in[1];
  const float* ea    = (const float*)d_in[2];
  const int*   batch = (const int*)d_in[3];
  const float* Wl1   = (const float*)d_in[4];
  const float* Wr1   = (const float*)d_in[5];
  const float* We1   = (const float*)d_in[6];
  const float* att1  = (const float*)d_in[7];
  const float* bias1 = (const float*)d_in[8];
  const float* Wl2   = (const float*)d_in[9];
  const float* Wr2   = (const float*)d_in[10];
  const float* We2   = (const float*)d_in[11];
  const float* att2  = (const float*)d_in[12];
  const float* bias2 = (const float*)d_in[13];
  const float* gam   = (const float*)d_in[14];
  const float* bet   = (const float*)d_in[15];
  const float* Wlin  = (const float*)d_in[16];
  const float* blin  = (const float*)d_in[17];
  float* out = (float*)d_out;
  const int* srcp = ei;
  const int* dstp = ei + EE;

  char* ws = (char*)d_ws;
  size_t off = 0;
  auto alloc = [&](size_t bytes) -> char* {
    char* p = ws + off;
    off = (off + bytes + 255) & ~(size_t)255;
    return p;
  };
  int*   offs    = (int*)  alloc((NN + 1) * 4);
  int*   cursor  = (int*)  alloc(NN * 4);
  int*   deg     = (int*)  alloc(NN * 4 + NN * DEA * 4);   // deg | esum contiguous
  float* esum    = (float*)(deg + NN);
  int*   csr_src = (int*)  alloc((size_t)EN * 4);
  float* csr_ea  = (float*)alloc((size_t)EN * EAS * 4);
  unsigned short* xlr = (unsigned short*)alloc((size_t)NN * SS * 2); // bf16, reused L1/L2
  float* h1      = (float*)alloc((size_t)NN * HC * 4);   // attn out (both layers)
  unsigned short* h1A = (unsigned short*)alloc((size_t)NN * HC * 2);
  unsigned short* W2t = (unsigned short*)alloc((size_t)SS * HC * 2);
  float* bnstat  = (float*)alloc(HC * 2 * 4);
  float* pooled  = (float*)alloc(GG * HC * 4 + GG * 4);  // pooled | cnt contiguous
  int*   cnt     = (int*)(pooled + GG * HC);

  // ---- preprocessing: self-loop attrs + CSR by dst ----
  hipMemsetAsync(deg, 0, NN * 4 + NN * DEA * 4, stream);
  k_deg_esum<<<(EE + 255) / 256, 256, 0, stream>>>(dstp, ea, deg, esum);
  k_scan<<<1, 1024, 0, stream>>>(deg, offs, cursor);
  k_scatter<<<(EN + 255) / 256, 256, 0, stream>>>(srcp, dstp, ea, esum, deg,
                                                  cursor, csr_src, csr_ea);

  // ---- layer 1 ----
  k_gemm1<<<(NN + 15) / 16, 256, 0, stream>>>(x, Wl1, Wr1, xlr);
  k_attn<<<NN * HH / 4, 256, 0, stream>>>(xlr, offs, csr_src, csr_ea,
                                          We1, att1, bias1, h1, 1);
  // ---- BN ----
  hipMemsetAsync(bnstat, 0, HC * 2 * 4, stream);
  k_bnstats<<<1024, HC, 0, stream>>>(h1, bnstat);
  k_bnapply<<<(NN * HC + 255) / 256, 256, 0, stream>>>(h1, bnstat, gam, bet, h1A);

  // ---- layer 2 ----
  k_w2t<<<(SS * HC + 255) / 256, 256, 0, stream>>>(Wl2, Wr2, W2t);
  dim3 g2((NN + 63) / 64, SS / 64);
  k_gemm2<<<g2, 256, 0, stream>>>(h1A, W2t, xlr);
  k_attn<<<NN * HH / 4, 256, 0, stream>>>(xlr, offs, csr_src, csr_ea,
                                          We2, att2, bias2, h1, 0);

  // ---- pool + final ----
  hipMemsetAsync(pooled, 0, GG * HC * 4 + GG * 4, stream);
  k_cnt<<<(NN + 255) / 256, 256, 0, stream>>>(batch, cnt);
  k_pool<<<640, HC, 0, stream>>>(h1, batch, pooled);
  k_final<<<1, HC, 0, stream>>>(pooled, cnt, gam, bet, Wlin, blin, out);
}

// Round 4
// 707.678 us; speedup vs baseline: 1.8945x; 1.2966x over previous
//
#include <hip/hip_runtime.h>
#include <hip/hip_bf16.h>

#define NN   20000
#define EE   320000
#define EN   340000   // EE + NN (self loops)
#define HH   8
#define CC   56
#define HC   448
#define SS   896      // fused xl|xr stride
#define DEA  5
#define EAS  8        // padded csr_ea stride (floats)
#define DINN 32
#define GG   32
#define NEG  0.2f

typedef short bf16x8 __attribute__((ext_vector_type(8)));
typedef float f32x4  __attribute__((ext_vector_type(4)));

static __device__ __forceinline__ unsigned short f2bf(float f) {
  unsigned int u = __float_as_uint(f);
  u += 0x7fffu + ((u >> 16) & 1u);   // round-to-nearest-even
  return (unsigned short)(u >> 16);
}

static __device__ __forceinline__ f32x4 bf4_to_f32x4(uint2 r) {
  f32x4 o;
  o.x = __uint_as_float(r.x << 16);
  o.y = __uint_as_float(r.x & 0xffff0000u);
  o.z = __uint_as_float(r.y << 16);
  o.w = __uint_as_float(r.y & 0xffff0000u);
  return o;
}

__global__ void k_deg_esum(const int* __restrict__ dst, const float* __restrict__ ea,
                           int* deg, float* esum) {
  int e = blockIdx.x * 256 + threadIdx.x;
  if (e >= EE) return;
  int d = dst[e];
  atomicAdd(&deg[d], 1);
  #pragma unroll
  for (int j = 0; j < DEA; j++) atomicAdd(&esum[d * DEA + j], ea[e * DEA + j]);
}

// exclusive scan of (deg[n]+1) -> offs[0..NN] and cursor[0..NN-1]
__global__ __launch_bounds__(1024) void k_scan(const int* __restrict__ deg, int* offs,
                                               int* cursor) {
  __shared__ int tot[1024];
  int t = threadIdx.x;
  int base = t * 20;
  int loc[20];
  int s = 0;
  #pragma unroll
  for (int i = 0; i < 20; i++) {
    int idx = base + i;
    int v = (idx < NN) ? deg[idx] + 1 : 0;
    loc[i] = s;           // thread-local exclusive prefix
    s += v;
  }
  tot[t] = s;
  __syncthreads();
  for (int o = 1; o < 1024; o <<= 1) {
    int v = (t >= o) ? tot[t - o] : 0;
    __syncthreads();
    tot[t] += v;
    __syncthreads();
  }
  int basesum = (t == 0) ? 0 : tot[t - 1];
  #pragma unroll
  for (int i = 0; i < 20; i++) {
    int idx = base + i;
    if (idx < NN) { offs[idx] = basesum + loc[i]; cursor[idx] = basesum + loc[i]; }
  }
  if (t == 1023) offs[NN] = tot[1023];
}

__global__ void k_scatter(const int* __restrict__ src, const int* __restrict__ dst,
                          const float* __restrict__ ea, const float* __restrict__ esum,
                          const int* __restrict__ deg,
                          int* cursor, int* __restrict__ csr_src, float* __restrict__ csr_ea) {
  int i = blockIdx.x * 256 + threadIdx.x;
  if (i >= EN) return;
  int s, d; float a[DEA];
  if (i < EE) {
    d = dst[i]; s = src[i];
    #pragma unroll
    for (int j = 0; j < DEA; j++) a[j] = ea[(size_t)i * DEA + j];
  } else {
    d = i - EE; s = d;
    float inv = 1.f / fmaxf((float)deg[d], 1.f);   // self-loop attr = mean of incoming
    #pragma unroll
    for (int j = 0; j < DEA; j++) a[j] = esum[(size_t)d * DEA + j] * inv;
  }
  int pos = atomicAdd(&cursor[d], 1);
  csr_src[pos] = s;
  float* o = csr_ea + (size_t)pos * EAS;
  #pragma unroll
  for (int j = 0; j < DEA; j++) o[j] = a[j];
}

// xlr[n, 0:448] = x @ Wl1 ; xlr[n, 448:896] = x @ Wr1 (K=32), 16 rows/block, bf16 out
__global__ __launch_bounds__(256) void k_gemm1(const float* __restrict__ x,
                                               const float* __restrict__ Wl,
                                               const float* __restrict__ Wr,
                                               unsigned short* __restrict__ out) {
  int n0 = blockIdx.x * 16;
  __shared__ float xs[16][DINN];
  int t = threadIdx.x;
  for (int i = t; i < 16 * DINN; i += 256) {
    int r = i >> 5, k = i & 31;
    int row = n0 + r;
    xs[r][k] = (row < NN) ? x[(size_t)row * DINN + k] : 0.f;
  }
  __syncthreads();
  for (int col = t; col < SS; col += 256) {
    const float* W = (col < HC) ? (Wl + col) : (Wr + (col - HC));
    float acc[16];
    #pragma unroll
    for (int r = 0; r < 16; r++) acc[r] = 0.f;
    for (int k = 0; k < DINN; k++) {
      float wk = W[k * HC];
      #pragma unroll
      for (int r = 0; r < 16; r++) acc[r] += xs[r][k] * wk;
    }
    #pragma unroll
    for (int r = 0; r < 16; r++) {
      int row = n0 + r;
      if (row < NN) out[(size_t)row * SS + col] = f2bf(acc[r]);
    }
  }
}

// Fused GATv2 attention: wave = (node, head); 4 edge-groups x 16 lanes,
// lane = 4 channels; bf16 xlr gathers; 2x edge unroll (8 gathers in flight).
__global__ __launch_bounds__(256) void k_attn(
    const unsigned short* __restrict__ xlr,
    const int* __restrict__ offs, const int* __restrict__ csr_src,
    const float* __restrict__ csr_ea,
    const float* __restrict__ We, const float* __restrict__ att,
    const float* __restrict__ bias, float* __restrict__ out, int apply_elu) {
  int wid = (blockIdx.x << 2) + (threadIdx.x >> 6);
  int n = wid >> 3;
  if (n >= NN) return;
  int h = wid & 7;
  int lane = threadIdx.x & 63;
  int grp  = lane >> 4;          // which edge in the 4-wide batch
  int gl   = lane & 15;          // lane within group
  bool cvalid = gl < 14;         // 14 lanes x 4ch = 56 channels
  int cj = cvalid ? gl : 13;     // clamp for safe loads
  int colbase = h * CC + cj * 4;

  f32x4 xr4 = bf4_to_f32x4(*(const uint2*)(xlr + (size_t)n * SS + HC + colbase));
  f32x4 att4 = *(const f32x4*)(att + colbase);
  if (!cvalid) att4 = (f32x4){0.f, 0.f, 0.f, 0.f};
  f32x4 w0 = *(const f32x4*)(We + 0 * HC + colbase);
  f32x4 w1 = *(const f32x4*)(We + 1 * HC + colbase);
  f32x4 w2 = *(const f32x4*)(We + 2 * HC + colbase);
  f32x4 w3 = *(const f32x4*)(We + 3 * HC + colbase);
  f32x4 w4 = *(const f32x4*)(We + 4 * HC + colbase);

  int e0 = offs[n], e1 = offs[n + 1];
  float l = 0.f;
  f32x4 acc = {0.f, 0.f, 0.f, 0.f};

  for (int e = e0 + grp; e < e1; e += 8) {
    int eb = e + 4;
    bool h2v = eb < e1;
    int ebc = h2v ? eb : e;
    int s0 = csr_src[e];
    int s1 = csr_src[ebc];
    const float* ep0 = csr_ea + (size_t)e * EAS;
    const float* ep1 = csr_ea + (size_t)ebc * EAS;
    f32x4 ea0 = *(const f32x4*)ep0;  float e40 = ep0[4];
    f32x4 ea1 = *(const f32x4*)ep1;  float e41 = ep1[4];
    uint2 r0 = *(const uint2*)(xlr + (size_t)s0 * SS + colbase);
    uint2 r1 = *(const uint2*)(xlr + (size_t)s1 * SS + colbase);
    f32x4 xl0 = bf4_to_f32x4(r0);
    f32x4 xl1 = bf4_to_f32x4(r1);

    f32x4 t0 = xl0 + xr4;
    t0 += ea0.x * w0; t0 += ea0.y * w1; t0 += ea0.z * w2; t0 += ea0.w * w3; t0 += e40 * w4;
    f32x4 t1 = xl1 + xr4;
    t1 += ea1.x * w0; t1 += ea1.y * w1; t1 += ea1.z * w2; t1 += ea1.w * w3; t1 += e41 * w4;
    t0.x = fmaxf(t0.x, NEG * t0.x); t0.y = fmaxf(t0.y, NEG * t0.y);
    t0.z = fmaxf(t0.z, NEG * t0.z); t0.w = fmaxf(t0.w, NEG * t0.w);
    t1.x = fmaxf(t1.x, NEG * t1.x); t1.y = fmaxf(t1.y, NEG * t1.y);
    t1.z = fmaxf(t1.z, NEG * t1.z); t1.w = fmaxf(t1.w, NEG * t1.w);
    float p0 = t0.x * att4.x + t0.y * att4.y + t0.z * att4.z + t0.w * att4.w;
    float p1 = t1.x * att4.x + t1.y * att4.y + t1.z * att4.z + t1.w * att4.w;
    p0 += __shfl_xor(p0, 1, 64);  p1 += __shfl_xor(p1, 1, 64);
    p0 += __shfl_xor(p0, 2, 64);  p1 += __shfl_xor(p1, 2, 64);
    p0 += __shfl_xor(p0, 4, 64);  p1 += __shfl_xor(p1, 4, 64);
    p0 += __shfl_xor(p0, 8, 64);  p1 += __shfl_xor(p1, 8, 64);
    float wv0 = __expf(fminf(p0, 60.f));
    float wv1 = h2v ? __expf(fminf(p1, 60.f)) : 0.f;
    acc += wv0 * xl0;
    acc += wv1 * xl1;
    l += wv0 + wv1;
  }
  // merge 4 groups (butterfly over xor 16, 32)
  l += __shfl_xor(l, 16, 64);
  l += __shfl_xor(l, 32, 64);
  acc.x += __shfl_xor(acc.x, 16, 64); acc.x += __shfl_xor(acc.x, 32, 64);
  acc.y += __shfl_xor(acc.y, 16, 64); acc.y += __shfl_xor(acc.y, 32, 64);
  acc.z += __shfl_xor(acc.z, 16, 64); acc.z += __shfl_xor(acc.z, 32, 64);
  acc.w += __shfl_xor(acc.w, 16, 64); acc.w += __shfl_xor(acc.w, 32, 64);

  if (lane < 14) {
    f32x4 b4 = *(const f32x4*)(bias + colbase);
    float inv = 1.f / (l + 1e-16f);
    f32x4 o = acc * inv + b4;
    if (apply_elu) {
      o.x = o.x > 0.f ? o.x : (__expf(o.x) - 1.f);
      o.y = o.y > 0.f ? o.y : (__expf(o.y) - 1.f);
      o.z = o.z > 0.f ? o.z : (__expf(o.z) - 1.f);
      o.w = o.w > 0.f ? o.w : (__expf(o.w) - 1.f);
    }
    *(f32x4*)(out + (size_t)n * HC + colbase) = o;
  }
}

// per-channel sum / sumsq over NN rows
__global__ __launch_bounds__(448) void k_bnstats(const float* __restrict__ h, float* stat) {
  int c = threadIdx.x;
  float s = 0.f, sq = 0.f;
  for (int r = blockIdx.x; r < NN; r += gridDim.x) {
    float v = h[(size_t)r * HC + c];
    s += v; sq += v * v;
  }
  atomicAdd(&stat[c], s);
  atomicAdd(&stat[HC + c], sq);
}

// BN finalize folded in: stat holds raw sum / sumsq
__global__ void k_bnapply(const float* __restrict__ h, const float* __restrict__ stat,
                          const float* __restrict__ gam, const float* __restrict__ bet,
                          unsigned short* __restrict__ hA) {
  int i = blockIdx.x * 256 + threadIdx.x;
  if (i >= NN * HC) return;
  int c = i % HC;
  float mean = stat[c] * (1.f / NN);
  float var  = stat[HC + c] * (1.f / NN) - mean * mean;
  float sc = rsqrtf(var + 1e-5f) * gam[c];
  float sh = bet[c] - mean * sc;
  hA[i] = f2bf(h[i] * sc + sh);
}

// W2t[nn][k] = (nn<448 ? Wl2 : Wr2)[k][nn mod 448], cast to bf16
__global__ void k_w2t(const float* __restrict__ Wl2, const float* __restrict__ Wr2,
                      unsigned short* __restrict__ Bt) {
  int i = blockIdx.x * 256 + threadIdx.x;
  if (i >= SS * HC) return;
  int nn = i / HC, k = i - nn * HC;
  float v = (nn < HC) ? Wl2[k * HC + nn] : Wr2[k * HC + (nn - HC)];
  Bt[nn * HC + k] = f2bf(v);
}

// LDS-staged bf16 MFMA GEMM (m97 structure): out[M=NN,896] = A[M,448]*Bt[896,448]^T
// 128x128 tile, BK=32, global_load_lds width-16 staging, 4 waves x 4x4 MFMA accs.
__global__ __launch_bounds__(256) void k_gemm2(const unsigned short* __restrict__ A,
                                               const unsigned short* __restrict__ Bt,
                                               unsigned short* __restrict__ out) {
  __shared__ unsigned short As[128 * 32];   // [row][k], 64 B/row, contiguous (lds-load order)
  __shared__ unsigned short Bs[128 * 32];
  int t = threadIdx.x;
  int w = t >> 6, lane = t & 63;
  int wm = w >> 1, wn = w & 1;
  int q = lane >> 4, r = lane & 15;
  int m0 = blockIdx.x * 128;
  int n0 = blockIdx.y * 128;

  // staging: 512 16B-segments per tile; thread t covers segments t and t+256.
  // segment s: row = s>>2, quarter = s&3 (8 bf16). LDS offset = s*16 bytes
  // (= wave-uniform base + lane*16, matching global_load_lds semantics).
  int s0 = t, s1 = t + 256;
  int ar0 = m0 + (s0 >> 2); if (ar0 >= NN) ar0 = NN - 1;
  int ar1 = m0 + (s1 >> 2); if (ar1 >= NN) ar1 = NN - 1;
  const unsigned short* ag0 = A + (size_t)ar0 * HC + (s0 & 3) * 8;
  const unsigned short* ag1 = A + (size_t)ar1 * HC + (s1 & 3) * 8;
  const unsigned short* bg0 = Bt + (size_t)(n0 + (s0 >> 2)) * HC + (s0 & 3) * 8;
  const unsigned short* bg1 = Bt + (size_t)(n0 + (s1 >> 2)) * HC + (s1 & 3) * 8;
  unsigned short* la0 = As + s0 * 8;
  unsigned short* la1 = As + s1 * 8;
  unsigned short* lb0 = Bs + s0 * 8;
  unsigned short* lb1 = Bs + s1 * 8;

  f32x4 zero = {0.f, 0.f, 0.f, 0.f};
  f32x4 acc[4][4];
  #pragma unroll
  for (int i = 0; i < 4; i++)
    #pragma unroll
    for (int j = 0; j < 4; j++) acc[i][j] = zero;

  for (int k0 = 0; k0 < HC; k0 += 32) {
    __builtin_amdgcn_global_load_lds(
        (const __attribute__((address_space(1))) unsigned int*)(ag0 + k0),
        (__attribute__((address_space(3))) unsigned int*)la0, 16, 0, 0);
    __builtin_amdgcn_global_load_lds(
        (const __attribute__((address_space(1))) unsigned int*)(ag1 + k0),
        (__attribute__((address_space(3))) unsigned int*)la1, 16, 0, 0);
    __builtin_amdgcn_global_load_lds(
        (const __attribute__((address_space(1))) unsigned int*)(bg0 + k0),
        (__attribute__((address_space(3))) unsigned int*)lb0, 16, 0, 0);
    __builtin_amdgcn_global_load_lds(
        (const __attribute__((address_space(1))) unsigned int*)(bg1 + k0),
        (__attribute__((address_space(3))) unsigned int*)lb1, 16, 0, 0);
    __syncthreads();   // compiler emits vmcnt(0) drain before barrier
    bf16x8 af[4], bf[4];
    #pragma unroll
    for (int i = 0; i < 4; i++)
      af[i] = *(const bf16x8*)(As + (wm * 64 + i * 16 + r) * 32 + q * 8);
    #pragma unroll
    for (int j = 0; j < 4; j++)
      bf[j] = *(const bf16x8*)(Bs + (wn * 64 + j * 16 + r) * 32 + q * 8);
    #pragma unroll
    for (int i = 0; i < 4; i++)
      #pragma unroll
      for (int j = 0; j < 4; j++)
        acc[i][j] = __builtin_amdgcn_mfma_f32_16x16x32_bf16(af[i], bf[j], acc[i][j], 0, 0, 0);
    __syncthreads();   // all waves done reading before next stage overwrites
  }

  #pragma unroll
  for (int i = 0; i < 4; i++) {
    int row_base = m0 + wm * 64 + i * 16 + q * 4;   // C/D: col=lane&15, row=quad*4+reg
    #pragma unroll
    for (int j = 0; j < 4; j++) {
      int col = n0 + wn * 64 + j * 16 + r;
      #pragma unroll
      for (int reg = 0; reg < 4; reg++) {
        int row = row_base + reg;
        if (row < NN) out[(size_t)row * SS + col] = f2bf(acc[i][j][reg]);
      }
    }
  }
}

// segment-sum pool over sorted batch; also counts rows per graph (thread 0)
__global__ __launch_bounds__(448) void k_pool(const float* __restrict__ h2,
                                              const int* __restrict__ batch,
                                              float* pooled, int* cnt) {
  int c = threadIdx.x;
  int rows_per = (NN + gridDim.x - 1) / gridDim.x;
  int r0 = blockIdx.x * rows_per, r1 = min(NN, r0 + rows_per);
  if (r0 >= r1) return;
  float loc = 0.f;
  int rc = 0;
  int gcur = batch[r0];
  for (int r = r0; r < r1; r++) {
    int g = batch[r];
    if (g != gcur) {
      atomicAdd(&pooled[gcur * HC + c], loc);
      if (c == 0) atomicAdd(&cnt[gcur], rc);
      loc = 0.f; rc = 0; gcur = g;
    }
    loc += h2[(size_t)r * HC + c];
    rc++;
  }
  atomicAdd(&pooled[gcur * HC + c], loc);
  if (c == 0) atomicAdd(&cnt[gcur], rc);
}

// pooled mean -> BN over 32 graphs -> logits -> log_softmax (single block)
__global__ __launch_bounds__(448) void k_final(const float* __restrict__ pooled_sum,
                                               const int* __restrict__ cnt,
                                               const float* __restrict__ gam,
                                               const float* __restrict__ bet,
                                               const float* __restrict__ Wlin,
                                               const float* __restrict__ blin,
                                               float* __restrict__ out) {
  __shared__ float P[GG * HC];
  __shared__ float L[GG * 18];
  __shared__ float red[GG];
  int c = threadIdx.x;
  float s = 0.f, sq = 0.f;
  for (int g = 0; g < GG; g++) {
    float v = pooled_sum[g * HC + c] / fmaxf((float)cnt[g], 1.f);
    P[g * HC + c] = v; s += v; sq += v * v;
  }
  float mean = s * (1.f / GG);
  float var  = sq * (1.f / GG) - mean * mean;
  float sc = rsqrtf(var + 1e-5f) * gam[c];
  float sh = bet[c] - mean * sc;
  for (int g = 0; g < GG; g++) P[g * HC + c] = P[g * HC + c] * sc + sh;
  __syncthreads();
  for (int o = c; o < GG * 18; o += HC) {
    int g = o / 18, j = o - g * 18;
    float acc = blin[j];
    for (int k = 0; k < HC; k++) acc += P[g * HC + k] * Wlin[k * 18 + j];
    L[o] = acc;
  }
  __syncthreads();
  if (c < GG) {
    float mx = -3.4e38f;
    for (int j = 0; j < 18; j++) mx = fmaxf(mx, L[c * 18 + j]);
    float se = 0.f;
    for (int j = 0; j < 18; j++) se += __expf(L[c * 18 + j] - mx);
    red[c] = mx + logf(se);
  }
  __syncthreads();
  for (int o = c; o < GG * 18; o += HC) out[o] = L[o] - red[o / 18];
}

extern "C" void kernel_launch(void* const* d_in, const int* in_sizes, int n_in,
                              void* d_out, int out_size, void* d_ws, size_t ws_size,
                              hipStream_t stream) {
  (void)in_sizes; (void)n_in; (void)out_size; (void)ws_size;
  const float* x     = (const float*)d_in[0];
  const int*   ei    = (const int*)d_in[1];
  const float* ea    = (const float*)d_in[2];
  const int*   batch = (const int*)d_in[3];
  const float* Wl1   = (const float*)d_in[4];
  const float* Wr1   = (const float*)d_in[5];
  const float* We1   = (const float*)d_in[6];
  const float* att1  = (const float*)d_in[7];
  const float* bias1 = (const float*)d_in[8];
  const float* Wl2   = (const float*)d_in[9];
  const float* Wr2   = (const float*)d_in[10];
  const float* We2   = (const float*)d_in[11];
  const float* att2  = (const float*)d_in[12];
  const float* bias2 = (const float*)d_in[13];
  const float* gam   = (const float*)d_in[14];
  const float* bet   = (const float*)d_in[15];
  const float* Wlin  = (const float*)d_in[16];
  const float* blin  = (const float*)d_in[17];
  float* out = (float*)d_out;
  const int* srcp = ei;
  const int* dstp = ei + EE;

  char* ws = (char*)d_ws;
  size_t off = 0;
  auto alloc = [&](size_t bytes) -> char* {
    char* p = ws + off;
    off = (off + bytes + 255) & ~(size_t)255;
    return p;
  };
  int*   offs    = (int*)  alloc((NN + 1) * 4);
  int*   cursor  = (int*)  alloc(NN * 4);
  int*   deg     = (int*)  alloc(NN * 4 + NN * DEA * 4);   // deg | esum contiguous
  float* esum    = (float*)(deg + NN);
  int*   csr_src = (int*)  alloc((size_t)EN * 4);
  float* csr_ea  = (float*)alloc((size_t)EN * EAS * 4);
  unsigned short* xlr = (unsigned short*)alloc((size_t)NN * SS * 2); // bf16, reused L1/L2
  float* h1      = (float*)alloc((size_t)NN * HC * 4);   // attn out (both layers)
  unsigned short* h1A = (unsigned short*)alloc((size_t)NN * HC * 2);
  unsigned short* W2t = (unsigned short*)alloc((size_t)SS * HC * 2);
  float* bnstat  = (float*)alloc(HC * 2 * 4);
  float* pooled  = (float*)alloc(GG * HC * 4 + GG * 4);  // pooled | cnt contiguous
  int*   cnt     = (int*)(pooled + GG * HC);

  // ---- preprocessing: self-loop attrs + CSR by dst ----
  hipMemsetAsync(deg, 0, NN * 4 + NN * DEA * 4, stream);
  k_deg_esum<<<(EE + 255) / 256, 256, 0, stream>>>(dstp, ea, deg, esum);
  k_scan<<<1, 1024, 0, stream>>>(deg, offs, cursor);
  k_scatter<<<(EN + 255) / 256, 256, 0, stream>>>(srcp, dstp, ea, esum, deg,
                                                  cursor, csr_src, csr_ea);

  // ---- layer 1 ----
  k_gemm1<<<(NN + 15) / 16, 256, 0, stream>>>(x, Wl1, Wr1, xlr);
  k_attn<<<NN * HH / 4, 256, 0, stream>>>(xlr, offs, csr_src, csr_ea,
                                          We1, att1, bias1, h1, 1);
  // ---- BN ----
  hipMemsetAsync(bnstat, 0, HC * 2 * 4, stream);
  k_bnstats<<<1024, HC, 0, stream>>>(h1, bnstat);
  k_bnapply<<<(NN * HC + 255) / 256, 256, 0, stream>>>(h1, bnstat, gam, bet, h1A);

  // ---- layer 2 ----
  k_w2t<<<(SS * HC + 255) / 256, 256, 0, stream>>>(Wl2, Wr2, W2t);
  dim3 g2((NN + 127) / 128, SS / 128);
  k_gemm2<<<g2, 256, 0, stream>>>(h1A, W2t, xlr);
  k_attn<<<NN * HH / 4, 256, 0, stream>>>(xlr, offs, csr_src, csr_ea,
                                          We2, att2, bias2, h1, 0);

  // ---- pool + final ----
  hipMemsetAsync(pooled, 0, GG * HC * 4 + GG * 4, stream);
  k_pool<<<640, HC, 0, stream>>>(h1, batch, pooled, cnt);
  k_final<<<1, HC, 0, stream>>>(pooled, cnt, gam, bet, Wlin, blin, out);
}

// Round 6
// 556.154 us; speedup vs baseline: 2.4107x; 1.2724x over previous
//
#include <hip/hip_runtime.h>
#include <hip/hip_bf16.h>

#define NN   20000
#define EE   320000
#define EN   340000   // EE + NN (self loops)
#define HH   8
#define CC   56
#define HC   448
#define SS   896      // fused xl|xr stride
#define DEA  5
#define EAS  8        // padded csr_ea stride (floats)
#define DINN 32
#define GG   32
#define NEG  0.2f

typedef short bf16x8 __attribute__((ext_vector_type(8)));
typedef float f32x4  __attribute__((ext_vector_type(4)));

static __device__ __forceinline__ unsigned short f2bf(float f) {
  unsigned int u = __float_as_uint(f);
  u += 0x7fffu + ((u >> 16) & 1u);   // round-to-nearest-even
  return (unsigned short)(u >> 16);
}

static __device__ __forceinline__ f32x4 bf4_to_f32x4(uint2 r) {
  f32x4 o;
  o.x = __uint_as_float(r.x << 16);
  o.y = __uint_as_float(r.x & 0xffff0000u);
  o.z = __uint_as_float(r.y << 16);
  o.w = __uint_as_float(r.y & 0xffff0000u);
  return o;
}

__global__ void k_deg(const int* __restrict__ dst, int* deg) {
  int e = blockIdx.x * 256 + threadIdx.x;
  if (e < EE) atomicAdd(&deg[dst[e]], 1);
}

// exclusive scan of (deg[n]+1) -> offs[0..NN] and cursor[0..NN-1]
__global__ __launch_bounds__(1024) void k_scan(const int* __restrict__ deg, int* offs,
                                               int* cursor) {
  __shared__ int tot[1024];
  int t = threadIdx.x;
  int base = t * 20;
  int loc[20];
  int s = 0;
  #pragma unroll
  for (int i = 0; i < 20; i++) {
    int idx = base + i;
    int v = (idx < NN) ? deg[idx] + 1 : 0;
    loc[i] = s;           // thread-local exclusive prefix
    s += v;
  }
  tot[t] = s;
  __syncthreads();
  for (int o = 1; o < 1024; o <<= 1) {
    int v = (t >= o) ? tot[t - o] : 0;
    __syncthreads();
    tot[t] += v;
    __syncthreads();
  }
  int basesum = (t == 0) ? 0 : tot[t - 1];
  #pragma unroll
  for (int i = 0; i < 20; i++) {
    int idx = base + i;
    if (idx < NN) { offs[idx] = basesum + loc[i]; cursor[idx] = basesum + loc[i]; }
  }
  if (t == 1023) offs[NN] = tot[1023];
}

// scatter real edges; slots [offs[n], offs[n+1]-1) — last slot reserved for self-loop
__global__ void k_scatter(const int* __restrict__ src, const int* __restrict__ dst,
                          const float* __restrict__ ea,
                          int* cursor, int* __restrict__ csr_src, float* __restrict__ csr_ea) {
  int i = blockIdx.x * 256 + threadIdx.x;
  if (i >= EE) return;
  int d = dst[i], s = src[i];
  float a[DEA];
  #pragma unroll
  for (int j = 0; j < DEA; j++) a[j] = ea[(size_t)i * DEA + j];
  int pos = atomicAdd(&cursor[d], 1);
  csr_src[pos] = s;
  float* o = csr_ea + (size_t)pos * EAS;
  #pragma unroll
  for (int j = 0; j < DEA; j++) o[j] = a[j];
}

// self-loop at slot offs[n+1]-1: attr = mean of the node's real incoming edge attrs
__global__ void k_selfloop(const int* __restrict__ offs,
                           int* __restrict__ csr_src, float* __restrict__ csr_ea) {
  int n = blockIdx.x * 256 + threadIdx.x;
  if (n >= NN) return;
  int e0 = offs[n], e1 = offs[n + 1] - 1;   // real edges in [e0, e1)
  float a0 = 0.f, a1 = 0.f, a2 = 0.f, a3 = 0.f, a4 = 0.f;
  for (int e = e0; e < e1; e++) {
    const float* p = csr_ea + (size_t)e * EAS;
    a0 += p[0]; a1 += p[1]; a2 += p[2]; a3 += p[3]; a4 += p[4];
  }
  float inv = 1.f / fmaxf((float)(e1 - e0), 1.f);
  csr_src[e1] = n;
  float* o = csr_ea + (size_t)e1 * EAS;
  o[0] = a0 * inv; o[1] = a1 * inv; o[2] = a2 * inv; o[3] = a3 * inv; o[4] = a4 * inv;
}

// cast x (20000x32 fp32) to bf16
__global__ void k_xcast(const float* __restrict__ x, unsigned short* __restrict__ xb) {
  int i = blockIdx.x * 256 + threadIdx.x;
  if (i < NN * DINN) xb[i] = f2bf(x[i]);
}

// Wt[col][k] = (col<448 ? Wl : Wr)[k][col mod 448] bf16; K = inner dim of W
__global__ void k_wt(const float* __restrict__ Wl, const float* __restrict__ Wr,
                     unsigned short* __restrict__ Bt, int K) {
  int i = blockIdx.x * 256 + threadIdx.x;
  if (i >= SS * K) return;
  int col = i / K, k = i - col * K;
  int cc = (col < HC) ? col : col - HC;     // 448 is NOT pow2 — no masking!
  const float* W = (col < HC) ? Wl : Wr;
  Bt[(size_t)col * K + k] = f2bf(W[(size_t)k * HC + cc]);
}

// MFMA gemm1: out[NN,896] = xb[NN,32] @ W1t[896,32]^T, bf16 out. One K-step.
__global__ __launch_bounds__(256) void k_gemm1(const unsigned short* __restrict__ xb,
                                               const unsigned short* __restrict__ W1t,
                                               unsigned short* __restrict__ out) {
  int w = threadIdx.x >> 6, lane = threadIdx.x & 63;
  int q = lane >> 4, r = lane & 15;
  int m0 = (blockIdx.x * 4 + w) * 16;
  int n0 = blockIdx.y * 64;
  int arow = m0 + r; if (arow >= NN) arow = NN - 1;
  bf16x8 a = *(const bf16x8*)(xb + (size_t)arow * DINN + q * 8);
  #pragma unroll
  for (int j = 0; j < 4; j++) {
    bf16x8 b = *(const bf16x8*)(W1t + (size_t)(n0 + j * 16 + r) * DINN + q * 8);
    f32x4 acc = {0.f, 0.f, 0.f, 0.f};
    acc = __builtin_amdgcn_mfma_f32_16x16x32_bf16(a, b, acc, 0, 0, 0);
    #pragma unroll
    for (int reg = 0; reg < 4; reg++) {
      int row = m0 + q * 4 + reg;         // C/D: col=lane&15, row=quad*4+reg
      if (row < NN) out[(size_t)row * SS + n0 + j * 16 + r] = f2bf(acc[reg]);
    }
  }
}

// Fused GATv2 attention: wave = (node, head); 4 edge-groups x 16 lanes,
// lane = 4 channels; bf16 xlr gathers; 2x edge unroll (8 gathers in flight).
__global__ __launch_bounds__(256) void k_attn(
    const unsigned short* __restrict__ xlr,
    const int* __restrict__ offs, const int* __restrict__ csr_src,
    const float* __restrict__ csr_ea,
    const float* __restrict__ We, const float* __restrict__ att,
    const float* __restrict__ bias, float* __restrict__ out, int apply_elu) {
  int wid = (blockIdx.x << 2) + (threadIdx.x >> 6);
  int n = wid >> 3;
  if (n >= NN) return;
  int h = wid & 7;
  int lane = threadIdx.x & 63;
  int grp  = lane >> 4;          // which edge in the 4-wide batch
  int gl   = lane & 15;          // lane within group
  bool cvalid = gl < 14;         // 14 lanes x 4ch = 56 channels
  int cj = cvalid ? gl : 13;     // clamp for safe loads
  int colbase = h * CC + cj * 4;

  f32x4 xr4 = bf4_to_f32x4(*(const uint2*)(xlr + (size_t)n * SS + HC + colbase));
  f32x4 att4 = *(const f32x4*)(att + colbase);
  if (!cvalid) att4 = (f32x4){0.f, 0.f, 0.f, 0.f};
  f32x4 w0 = *(const f32x4*)(We + 0 * HC + colbase);
  f32x4 w1 = *(const f32x4*)(We + 1 * HC + colbase);
  f32x4 w2 = *(const f32x4*)(We + 2 * HC + colbase);
  f32x4 w3 = *(const f32x4*)(We + 3 * HC + colbase);
  f32x4 w4 = *(const f32x4*)(We + 4 * HC + colbase);

  int e0 = offs[n], e1 = offs[n + 1];
  float l = 0.f;
  f32x4 acc = {0.f, 0.f, 0.f, 0.f};

  for (int e = e0 + grp; e < e1; e += 8) {
    int eb = e + 4;
    bool h2v = eb < e1;
    int ebc = h2v ? eb : e;
    int s0 = csr_src[e];
    int s1 = csr_src[ebc];
    const float* ep0 = csr_ea + (size_t)e * EAS;
    const float* ep1 = csr_ea + (size_t)ebc * EAS;
    f32x4 ea0 = *(const f32x4*)ep0;  float e40 = ep0[4];
    f32x4 ea1 = *(const f32x4*)ep1;  float e41 = ep1[4];
    uint2 r0 = *(const uint2*)(xlr + (size_t)s0 * SS + colbase);
    uint2 r1 = *(const uint2*)(xlr + (size_t)s1 * SS + colbase);
    f32x4 xl0 = bf4_to_f32x4(r0);
    f32x4 xl1 = bf4_to_f32x4(r1);

    f32x4 t0 = xl0 + xr4;
    t0 += ea0.x * w0; t0 += ea0.y * w1; t0 += ea0.z * w2; t0 += ea0.w * w3; t0 += e40 * w4;
    f32x4 t1 = xl1 + xr4;
    t1 += ea1.x * w0; t1 += ea1.y * w1; t1 += ea1.z * w2; t1 += ea1.w * w3; t1 += e41 * w4;
    t0.x = fmaxf(t0.x, NEG * t0.x); t0.y = fmaxf(t0.y, NEG * t0.y);
    t0.z = fmaxf(t0.z, NEG * t0.z); t0.w = fmaxf(t0.w, NEG * t0.w);
    t1.x = fmaxf(t1.x, NEG * t1.x); t1.y = fmaxf(t1.y, NEG * t1.y);
    t1.z = fmaxf(t1.z, NEG * t1.z); t1.w = fmaxf(t1.w, NEG * t1.w);
    float p0 = t0.x * att4.x + t0.y * att4.y + t0.z * att4.z + t0.w * att4.w;
    float p1 = t1.x * att4.x + t1.y * att4.y + t1.z * att4.z + t1.w * att4.w;
    p0 += __shfl_xor(p0, 1, 64);  p1 += __shfl_xor(p1, 1, 64);
    p0 += __shfl_xor(p0, 2, 64);  p1 += __shfl_xor(p1, 2, 64);
    p0 += __shfl_xor(p0, 4, 64);  p1 += __shfl_xor(p1, 4, 64);
    p0 += __shfl_xor(p0, 8, 64);  p1 += __shfl_xor(p1, 8, 64);
    float wv0 = __expf(fminf(p0, 60.f));
    float wv1 = h2v ? __expf(fminf(p1, 60.f)) : 0.f;
    acc += wv0 * xl0;
    acc += wv1 * xl1;
    l += wv0 + wv1;
  }
  // merge 4 groups (butterfly over xor 16, 32)
  l += __shfl_xor(l, 16, 64);
  l += __shfl_xor(l, 32, 64);
  acc.x += __shfl_xor(acc.x, 16, 64); acc.x += __shfl_xor(acc.x, 32, 64);
  acc.y += __shfl_xor(acc.y, 16, 64); acc.y += __shfl_xor(acc.y, 32, 64);
  acc.z += __shfl_xor(acc.z, 16, 64); acc.z += __shfl_xor(acc.z, 32, 64);
  acc.w += __shfl_xor(acc.w, 16, 64); acc.w += __shfl_xor(acc.w, 32, 64);

  if (lane < 14) {
    f32x4 b4 = *(const f32x4*)(bias + colbase);
    float inv = 1.f / (l + 1e-16f);
    f32x4 o = acc * inv + b4;
    if (apply_elu) {
      o.x = o.x > 0.f ? o.x : (__expf(o.x) - 1.f);
      o.y = o.y > 0.f ? o.y : (__expf(o.y) - 1.f);
      o.z = o.z > 0.f ? o.z : (__expf(o.z) - 1.f);
      o.w = o.w > 0.f ? o.w : (__expf(o.w) - 1.f);
    }
    *(f32x4*)(out + (size_t)n * HC + colbase) = o;
  }
}

// per-channel sum / sumsq over NN rows; contiguous row chunks per block
__global__ __launch_bounds__(448) void k_bnstats(const float* __restrict__ h, float* stat) {
  int c = threadIdx.x;
  int rows_per = (NN + gridDim.x - 1) / gridDim.x;
  int r0 = blockIdx.x * rows_per, r1 = min(NN, r0 + rows_per);
  float s = 0.f, sq = 0.f;
  for (int r = r0; r < r1; r++) {
    float v = h[(size_t)r * HC + c];
    s += v; sq += v * v;
  }
  atomicAdd(&stat[c], s);
  atomicAdd(&stat[HC + c], sq);
}

// BN finalize folded in: stat holds raw sum / sumsq
__global__ void k_bnapply(const float* __restrict__ h, const float* __restrict__ stat,
                          const float* __restrict__ gam, const float* __restrict__ bet,
                          unsigned short* __restrict__ hA) {
  int i = blockIdx.x * 256 + threadIdx.x;
  if (i >= NN * HC) return;
  int c = i % HC;
  float mean = stat[c] * (1.f / NN);
  float var  = stat[HC + c] * (1.f / NN) - mean * mean;
  float sc = rsqrtf(var + 1e-5f) * gam[c];
  float sh = bet[c] - mean * sc;
  hA[i] = f2bf(h[i] * sc + sh);
}

// LDS-staged bf16 MFMA GEMM: out[M=NN,896] = A[M,448]*Bt[896,448]^T, BK=64.
// 128x128 tile, global_load_lds width-16 staging, 4 waves x 4x4 MFMA accs.
__global__ __launch_bounds__(256) void k_gemm2(const unsigned short* __restrict__ A,
                                               const unsigned short* __restrict__ Bt,
                                               unsigned short* __restrict__ out) {
  __shared__ unsigned short As[128 * 64];   // [row][k], 128 B/row (lds-load order)
  __shared__ unsigned short Bs[128 * 64];
  int t = threadIdx.x;
  int w = t >> 6, lane = t & 63;
  int wm = w >> 1, wn = w & 1;
  int q = lane >> 4, r = lane & 15;
  int m0 = blockIdx.x * 128;
  int n0 = blockIdx.y * 128;

  // staging: 1024 16B-segments per matrix; thread t covers s = t + j*256, j=0..3.
  // segment s: row = s>>3, part = s&7 (8 bf16). LDS offset = s*16 bytes.
  const unsigned short *ag[4], *bg[4];
  unsigned short *la[4], *lb[4];
  #pragma unroll
  for (int j = 0; j < 4; j++) {
    int s = t + j * 256;
    int row = s >> 3, part = s & 7;
    int ar = m0 + row; if (ar >= NN) ar = NN - 1;
    ag[j] = A + (size_t)ar * HC + part * 8;
    bg[j] = Bt + (size_t)(n0 + row) * HC + part * 8;
    la[j] = As + s * 8;
    lb[j] = Bs + s * 8;
  }

  f32x4 zero = {0.f, 0.f, 0.f, 0.f};
  f32x4 acc[4][4];
  #pragma unroll
  for (int i = 0; i < 4; i++)
    #pragma unroll
    for (int j = 0; j < 4; j++) acc[i][j] = zero;

  for (int k0 = 0; k0 < HC; k0 += 64) {
    #pragma unroll
    for (int j = 0; j < 4; j++) {
      __builtin_amdgcn_global_load_lds(
          (const __attribute__((address_space(1))) unsigned int*)(ag[j] + k0),
          (__attribute__((address_space(3))) unsigned int*)la[j], 16, 0, 0);
      __builtin_amdgcn_global_load_lds(
          (const __attribute__((address_space(1))) unsigned int*)(bg[j] + k0),
          (__attribute__((address_space(3))) unsigned int*)lb[j], 16, 0, 0);
    }
    __syncthreads();
    #pragma unroll
    for (int kk = 0; kk < 64; kk += 32) {
      bf16x8 af[4], bf[4];
      #pragma unroll
      for (int i = 0; i < 4; i++)
        af[i] = *(const bf16x8*)(As + (wm * 64 + i * 16 + r) * 64 + kk + q * 8);
      #pragma unroll
      for (int j = 0; j < 4; j++)
        bf[j] = *(const bf16x8*)(Bs + (wn * 64 + j * 16 + r) * 64 + kk + q * 8);
      #pragma unroll
      for (int i = 0; i < 4; i++)
        #pragma unroll
        for (int j = 0; j < 4; j++)
          acc[i][j] = __builtin_amdgcn_mfma_f32_16x16x32_bf16(af[i], bf[j], acc[i][j], 0, 0, 0);
    }
    __syncthreads();
  }

  #pragma unroll
  for (int i = 0; i < 4; i++) {
    int row_base = m0 + wm * 64 + i * 16 + q * 4;   // C/D: col=lane&15, row=quad*4+reg
    #pragma unroll
    for (int j = 0; j < 4; j++) {
      int col = n0 + wn * 64 + j * 16 + r;
      #pragma unroll
      for (int reg = 0; reg < 4; reg++) {
        int row = row_base + reg;
        if (row < NN) out[(size_t)row * SS + col] = f2bf(acc[i][j][reg]);
      }
    }
  }
}

// segment-sum pool over sorted batch; also counts rows per graph (thread 0)
__global__ __launch_bounds__(448) void k_pool(const float* __restrict__ h2,
                                              const int* __restrict__ batch,
                                              float* pooled, int* cnt) {
  int c = threadIdx.x;
  int rows_per = (NN + gridDim.x - 1) / gridDim.x;
  int r0 = blockIdx.x * rows_per, r1 = min(NN, r0 + rows_per);
  if (r0 >= r1) return;
  float loc = 0.f;
  int rc = 0;
  int gcur = batch[r0];
  for (int r = r0; r < r1; r++) {
    int g = batch[r];
    if (g != gcur) {
      atomicAdd(&pooled[gcur * HC + c], loc);
      if (c == 0) atomicAdd(&cnt[gcur], rc);
      loc = 0.f; rc = 0; gcur = g;
    }
    loc += h2[(size_t)r * HC + c];
    rc++;
  }
  atomicAdd(&pooled[gcur * HC + c], loc);
  if (c == 0) atomicAdd(&cnt[gcur], rc);
}

// pooled mean -> BN over 32 graphs -> logits -> log_softmax (single block)
__global__ __launch_bounds__(448) void k_final(const float* __restrict__ pooled_sum,
                                               const int* __restrict__ cnt,
                                               const float* __restrict__ gam,
                                               const float* __restrict__ bet,
                                               const float* __restrict__ Wlin,
                                               const float* __restrict__ blin,
                                               float* __restrict__ out) {
  __shared__ float P[GG * HC];
  __shared__ float L[GG * 18];
  __shared__ float red[GG];
  int c = threadIdx.x;
  float s = 0.f, sq = 0.f;
  for (int g = 0; g < GG; g++) {
    float v = pooled_sum[g * HC + c] / fmaxf((float)cnt[g], 1.f);
    P[g * HC + c] = v; s += v; sq += v * v;
  }
  float mean = s * (1.f / GG);
  float var  = sq * (1.f / GG) - mean * mean;
  float sc = rsqrtf(var + 1e-5f) * gam[c];
  float sh = bet[c] - mean * sc;
  for (int g = 0; g < GG; g++) P[g * HC + c] = P[g * HC + c] * sc + sh;
  __syncthreads();
  for (int o = c; o < GG * 18; o += HC) {
    int g = o / 18, j = o - g * 18;
    float acc = blin[j];
    for (int k = 0; k < HC; k++) acc += P[g * HC + k] * Wlin[k * 18 + j];
    L[o] = acc;
  }
  __syncthreads();
  if (c < GG) {
    float mx = -3.4e38f;
    for (int j = 0; j < 18; j++) mx = fmaxf(mx, L[c * 18 + j]);
    float se = 0.f;
    for (int j = 0; j < 18; j++) se += __expf(L[c * 18 + j] - mx);
    red[c] = mx + logf(se);
  }
  __syncthreads();
  for (int o = c; o < GG * 18; o += HC) out[o] = L[o] - red[o / 18];
}

extern "C" void kernel_launch(void* const* d_in, const int* in_sizes, int n_in,
                              void* d_out, int out_size, void* d_ws, size_t ws_size,
                              hipStream_t stream) {
  (void)in_sizes; (void)n_in; (void)out_size; (void)ws_size;
  const float* x     = (const float*)d_in[0];
  const int*   ei    = (const int*)d_in[1];
  const float* ea    = (const float*)d_in[2];
  const int*   batch = (const int*)d_in[3];
  const float* Wl1   = (const float*)d_in[4];
  const float* Wr1   = (const float*)d_in[5];
  const float* We1   = (const float*)d_in[6];
  const float* att1  = (const float*)d_in[7];
  const float* bias1 = (const float*)d_in[8];
  const float* Wl2   = (const float*)d_in[9];
  const float* Wr2   = (const float*)d_in[10];
  const float* We2   = (const float*)d_in[11];
  const float* att2  = (const float*)d_in[12];
  const float* bias2 = (const float*)d_in[13];
  const float* gam   = (const float*)d_in[14];
  const float* bet   = (const float*)d_in[15];
  const float* Wlin  = (const float*)d_in[16];
  const float* blin  = (const float*)d_in[17];
  float* out = (float*)d_out;
  const int* srcp = ei;
  const int* dstp = ei + EE;

  char* ws = (char*)d_ws;
  size_t off = 0;
  auto alloc = [&](size_t bytes) -> char* {
    char* p = ws + off;
    off = (off + bytes + 255) & ~(size_t)255;
    return p;
  };
  int*   offs    = (int*)  alloc((NN + 1) * 4);
  int*   cursor  = (int*)  alloc(NN * 4);
  int*   deg     = (int*)  alloc(NN * 4);
  int*   csr_src = (int*)  alloc((size_t)EN * 4);
  float* csr_ea  = (float*)alloc((size_t)EN * EAS * 4);
  unsigned short* xlr = (unsigned short*)alloc((size_t)NN * SS * 2); // bf16, reused L1/L2
  float* h1      = (float*)alloc((size_t)NN * HC * 4);   // attn out (both layers)
  unsigned short* h1A = (unsigned short*)alloc((size_t)NN * HC * 2);
  unsigned short* xb  = (unsigned short*)alloc((size_t)NN * DINN * 2);
  unsigned short* W1t = (unsigned short*)alloc((size_t)SS * DINN * 2);
  unsigned short* W2t = (unsigned short*)alloc((size_t)SS * HC * 2);
  float* bnstat  = (float*)alloc(HC * 2 * 4);
  float* pooled  = (float*)alloc(GG * HC * 4 + GG * 4);  // pooled | cnt contiguous
  int*   cnt     = (int*)(pooled + GG * HC);

  // ---- preprocessing: CSR by dst, self-loop attr from CSR ----
  hipMemsetAsync(deg, 0, NN * 4, stream);
  k_deg<<<(EE + 255) / 256, 256, 0, stream>>>(dstp, deg);
  k_scan<<<1, 1024, 0, stream>>>(deg, offs, cursor);
  k_scatter<<<(EE + 255) / 256, 256, 0, stream>>>(srcp, dstp, ea, cursor, csr_src, csr_ea);
  k_selfloop<<<(NN + 255) / 256, 256, 0, stream>>>(offs, csr_src, csr_ea);

  // ---- weight / input casts ----
  k_xcast<<<(NN * DINN + 255) / 256, 256, 0, stream>>>(x, xb);
  k_wt<<<(SS * DINN + 255) / 256, 256, 0, stream>>>(Wl1, Wr1, W1t, DINN);
  k_wt<<<(SS * HC + 255) / 256, 256, 0, stream>>>(Wl2, Wr2, W2t, HC);

  // ---- layer 1 ----
  dim3 g1((NN + 63) / 64, SS / 64);
  k_gemm1<<<g1, 256, 0, stream>>>(xb, W1t, xlr);
  k_attn<<<NN * HH / 4, 256, 0, stream>>>(xlr, offs, csr_src, csr_ea,
                                          We1, att1, bias1, h1, 1);
  // ---- BN ----
  hipMemsetAsync(bnstat, 0, HC * 2 * 4, stream);
  k_bnstats<<<256, HC, 0, stream>>>(h1, bnstat);
  k_bnapply<<<(NN * HC + 255) / 256, 256, 0, stream>>>(h1, bnstat, gam, bet, h1A);

  // ---- layer 2 ----
  dim3 g2((NN + 127) / 128, SS / 128);
  k_gemm2<<<g2, 256, 0, stream>>>(h1A, W2t, xlr);
  k_attn<<<NN * HH / 4, 256, 0, stream>>>(xlr, offs, csr_src, csr_ea,
                                          We2, att2, bias2, h1, 0);

  // ---- pool + final ----
  hipMemsetAsync(pooled, 0, GG * HC * 4 + GG * 4, stream);
  k_pool<<<640, HC, 0, stream>>>(h1, batch, pooled, cnt);
  k_final<<<1, HC, 0, stream>>>(pooled, cnt, gam, bet, Wlin, blin, out);
}

// Round 7
// 545.993 us; speedup vs baseline: 2.4556x; 1.0186x over previous
//
#include <hip/hip_runtime.h>
#include <hip/hip_bf16.h>

#define NN   20000
#define EE   320000
#define EN   340000   // EE + NN (self loops)
#define HH   8
#define CC   56
#define HC   448
#define SS   896      // fused xl|xr stride
#define DEA  5
#define EAS  8        // padded csr_ea stride (floats)
#define DINN 32
#define GG   32
#define NEG  0.2f

#define MT   157      // gemm2 M-tiles (ceil(20000/128))
#define NT   7        // gemm2 N-tiles (896/128)

typedef short bf16x8 __attribute__((ext_vector_type(8)));
typedef float f32x4  __attribute__((ext_vector_type(4)));

static __device__ __forceinline__ unsigned short f2bf(float f) {
  unsigned int u = __float_as_uint(f);
  u += 0x7fffu + ((u >> 16) & 1u);   // round-to-nearest-even
  return (unsigned short)(u >> 16);
}

static __device__ __forceinline__ f32x4 bf4_to_f32x4(uint2 r) {
  f32x4 o;
  o.x = __uint_as_float(r.x << 16);
  o.y = __uint_as_float(r.x & 0xffff0000u);
  o.z = __uint_as_float(r.y << 16);
  o.w = __uint_as_float(r.y & 0xffff0000u);
  return o;
}

__global__ void k_deg(const int* __restrict__ dst, int* deg) {
  int e = blockIdx.x * 256 + threadIdx.x;
  if (e < EE) atomicAdd(&deg[dst[e]], 1);
}

// exclusive scan of (deg[n]+1) -> offs[0..NN] and cursor[0..NN-1]
__global__ __launch_bounds__(1024) void k_scan(const int* __restrict__ deg, int* offs,
                                               int* cursor) {
  __shared__ int tot[1024];
  int t = threadIdx.x;
  int base = t * 20;
  int loc[20];
  int s = 0;
  #pragma unroll
  for (int i = 0; i < 20; i++) {
    int idx = base + i;
    int v = (idx < NN) ? deg[idx] + 1 : 0;
    loc[i] = s;           // thread-local exclusive prefix
    s += v;
  }
  tot[t] = s;
  __syncthreads();
  for (int o = 1; o < 1024; o <<= 1) {
    int v = (t >= o) ? tot[t - o] : 0;
    __syncthreads();
    tot[t] += v;
    __syncthreads();
  }
  int basesum = (t == 0) ? 0 : tot[t - 1];
  #pragma unroll
  for (int i = 0; i < 20; i++) {
    int idx = base + i;
    if (idx < NN) { offs[idx] = basesum + loc[i]; cursor[idx] = basesum + loc[i]; }
  }
  if (t == 1023) offs[NN] = tot[1023];
}

// scatter real edges; slots [offs[n], offs[n+1]-1) — last slot reserved for self-loop
__global__ void k_scatter(const int* __restrict__ src, const int* __restrict__ dst,
                          const float* __restrict__ ea,
                          int* cursor, int* __restrict__ csr_src, float* __restrict__ csr_ea) {
  int i = blockIdx.x * 256 + threadIdx.x;
  if (i >= EE) return;
  int d = dst[i], s = src[i];
  float a[DEA];
  #pragma unroll
  for (int j = 0; j < DEA; j++) a[j] = ea[(size_t)i * DEA + j];
  int pos = atomicAdd(&cursor[d], 1);
  csr_src[pos] = s;
  float* o = csr_ea + (size_t)pos * EAS;
  #pragma unroll
  for (int j = 0; j < DEA; j++) o[j] = a[j];
}

// fused: self-loop attrs + x->bf16 cast + W1t/W2t transposed bf16 casts
#define XCN (NN * DINN)
#define W1N (SS * DINN)
#define W2N (SS * HC)
__global__ void k_aux(const int* __restrict__ offs,
                      int* __restrict__ csr_src, float* __restrict__ csr_ea,
                      const float* __restrict__ x, unsigned short* __restrict__ xb,
                      const float* __restrict__ Wl1, const float* __restrict__ Wr1,
                      unsigned short* __restrict__ W1t,
                      const float* __restrict__ Wl2, const float* __restrict__ Wr2,
                      unsigned short* __restrict__ W2t) {
  int i = blockIdx.x * 256 + threadIdx.x;
  if (i < NN) {
    int n = i;
    int e0 = offs[n], e1 = offs[n + 1] - 1;   // real edges in [e0, e1)
    float a0 = 0.f, a1 = 0.f, a2 = 0.f, a3 = 0.f, a4 = 0.f;
    for (int e = e0; e < e1; e++) {
      const float* p = csr_ea + (size_t)e * EAS;
      a0 += p[0]; a1 += p[1]; a2 += p[2]; a3 += p[3]; a4 += p[4];
    }
    float inv = 1.f / fmaxf((float)(e1 - e0), 1.f);
    csr_src[e1] = n;
    float* o = csr_ea + (size_t)e1 * EAS;
    o[0] = a0 * inv; o[1] = a1 * inv; o[2] = a2 * inv; o[3] = a3 * inv; o[4] = a4 * inv;
    return;
  }
  i -= NN;
  if (i < XCN) { xb[i] = f2bf(x[i]); return; }
  i -= XCN;
  if (i < W1N) {
    int col = i / DINN, k = i - col * DINN;
    int cc = (col < HC) ? col : col - HC;
    const float* W = (col < HC) ? Wl1 : Wr1;
    W1t[i] = f2bf(W[(size_t)k * HC + cc]);
    return;
  }
  i -= W1N;
  if (i < W2N) {
    int col = i / HC, k = i - col * HC;
    int cc = (col < HC) ? col : col - HC;
    const float* W = (col < HC) ? Wl2 : Wr2;
    W2t[i] = f2bf(W[(size_t)k * HC + cc]);
  }
}

// MFMA gemm1: out[NN,896] = xb[NN,32] @ W1t[896,32]^T, bf16 out. One K-step.
__global__ __launch_bounds__(256) void k_gemm1(const unsigned short* __restrict__ xb,
                                               const unsigned short* __restrict__ W1t,
                                               unsigned short* __restrict__ out) {
  int w = threadIdx.x >> 6, lane = threadIdx.x & 63;
  int q = lane >> 4, r = lane & 15;
  int m0 = (blockIdx.x * 4 + w) * 16;
  int n0 = blockIdx.y * 64;
  int arow = m0 + r; if (arow >= NN) arow = NN - 1;
  bf16x8 a = *(const bf16x8*)(xb + (size_t)arow * DINN + q * 8);
  #pragma unroll
  for (int j = 0; j < 4; j++) {
    bf16x8 b = *(const bf16x8*)(W1t + (size_t)(n0 + j * 16 + r) * DINN + q * 8);
    f32x4 acc = {0.f, 0.f, 0.f, 0.f};
    acc = __builtin_amdgcn_mfma_f32_16x16x32_bf16(a, b, acc, 0, 0, 0);
    #pragma unroll
    for (int reg = 0; reg < 4; reg++) {
      int row = m0 + q * 4 + reg;         // C/D: col=lane&15, row=quad*4+reg
      if (row < NN) out[(size_t)row * SS + n0 + j * 16 + r] = f2bf(acc[reg]);
    }
  }
}

// Fused GATv2 attention, head-paired: wave = (node, head-pair); 4 edge-groups x
// 16 lanes; lane = 4 channels of head 2hp AND 4 channels of head 2hp+1 (+56 ch
// = +112 B, folds into load offset). 2x edge unroll -> 4 gathers in flight.
__global__ __launch_bounds__(256) void k_attn(
    const unsigned short* __restrict__ xlr,
    const int* __restrict__ offs, const int* __restrict__ csr_src,
    const float* __restrict__ csr_ea,
    const float* __restrict__ We, const float* __restrict__ att,
    const float* __restrict__ bias, float* __restrict__ out, int apply_elu) {
  int wid = (blockIdx.x << 2) + (threadIdx.x >> 6);
  int n = wid >> 2;
  if (n >= NN) return;
  int hp = wid & 3;              // heads 2hp, 2hp+1
  int lane = threadIdx.x & 63;
  int grp  = lane >> 4;
  int gl   = lane & 15;
  bool cvalid = gl < 14;
  int cj = cvalid ? gl : 13;
  int cb = hp * 112 + cj * 4;    // head A base; head B at cb+56

  const unsigned short* xrrow = xlr + (size_t)n * SS + HC;
  f32x4 xrA = bf4_to_f32x4(*(const uint2*)(xrrow + cb));
  f32x4 xrB = bf4_to_f32x4(*(const uint2*)(xrrow + cb + 56));
  f32x4 atA = *(const f32x4*)(att + cb);
  f32x4 atB = *(const f32x4*)(att + cb + 56);
  if (!cvalid) { atA = (f32x4){0,0,0,0}; atB = (f32x4){0,0,0,0}; }
  f32x4 wA[5], wB[5];
  #pragma unroll
  for (int j = 0; j < 5; j++) {
    wA[j] = *(const f32x4*)(We + j * HC + cb);
    wB[j] = *(const f32x4*)(We + j * HC + cb + 56);
  }

  int e0 = offs[n], e1 = offs[n + 1];
  float lA = 0.f, lB = 0.f;
  f32x4 accA = {0.f, 0.f, 0.f, 0.f};
  f32x4 accB = {0.f, 0.f, 0.f, 0.f};

  for (int e = e0 + grp; e < e1; e += 8) {
    int eb = e + 4;
    bool h2v = eb < e1;
    int ebc = h2v ? eb : e;
    int s0 = csr_src[e];
    int s1 = csr_src[ebc];
    const float* ep0 = csr_ea + (size_t)e * EAS;
    const float* ep1 = csr_ea + (size_t)ebc * EAS;
    f32x4 ea0 = *(const f32x4*)ep0;  float e40 = ep0[4];
    f32x4 ea1 = *(const f32x4*)ep1;  float e41 = ep1[4];
    const unsigned short* row0 = xlr + (size_t)s0 * SS + cb;
    const unsigned short* row1 = xlr + (size_t)s1 * SS + cb;
    uint2 r0a = *(const uint2*)(row0);
    uint2 r0b = *(const uint2*)(row0 + 56);
    uint2 r1a = *(const uint2*)(row1);
    uint2 r1b = *(const uint2*)(row1 + 56);
    f32x4 xl0a = bf4_to_f32x4(r0a), xl0b = bf4_to_f32x4(r0b);
    f32x4 xl1a = bf4_to_f32x4(r1a), xl1b = bf4_to_f32x4(r1b);

    f32x4 t0a = xl0a + xrA;
    t0a += ea0.x*wA[0]; t0a += ea0.y*wA[1]; t0a += ea0.z*wA[2]; t0a += ea0.w*wA[3]; t0a += e40*wA[4];
    f32x4 t0b = xl0b + xrB;
    t0b += ea0.x*wB[0]; t0b += ea0.y*wB[1]; t0b += ea0.z*wB[2]; t0b += ea0.w*wB[3]; t0b += e40*wB[4];
    f32x4 t1a = xl1a + xrA;
    t1a += ea1.x*wA[0]; t1a += ea1.y*wA[1]; t1a += ea1.z*wA[2]; t1a += ea1.w*wA[3]; t1a += e41*wA[4];
    f32x4 t1b = xl1b + xrB;
    t1b += ea1.x*wB[0]; t1b += ea1.y*wB[1]; t1b += ea1.z*wB[2]; t1b += ea1.w*wB[3]; t1b += e41*wB[4];

    t0a.x=fmaxf(t0a.x,NEG*t0a.x); t0a.y=fmaxf(t0a.y,NEG*t0a.y); t0a.z=fmaxf(t0a.z,NEG*t0a.z); t0a.w=fmaxf(t0a.w,NEG*t0a.w);
    t0b.x=fmaxf(t0b.x,NEG*t0b.x); t0b.y=fmaxf(t0b.y,NEG*t0b.y); t0b.z=fmaxf(t0b.z,NEG*t0b.z); t0b.w=fmaxf(t0b.w,NEG*t0b.w);
    t1a.x=fmaxf(t1a.x,NEG*t1a.x); t1a.y=fmaxf(t1a.y,NEG*t1a.y); t1a.z=fmaxf(t1a.z,NEG*t1a.z); t1a.w=fmaxf(t1a.w,NEG*t1a.w);
    t1b.x=fmaxf(t1b.x,NEG*t1b.x); t1b.y=fmaxf(t1b.y,NEG*t1b.y); t1b.z=fmaxf(t1b.z,NEG*t1b.z); t1b.w=fmaxf(t1b.w,NEG*t1b.w);

    float p0a = t0a.x*atA.x + t0a.y*atA.y + t0a.z*atA.z + t0a.w*atA.w;
    float p0b = t0b.x*atB.x + t0b.y*atB.y + t0b.z*atB.z + t0b.w*atB.w;
    float p1a = t1a.x*atA.x + t1a.y*atA.y + t1a.z*atA.z + t1a.w*atA.w;
    float p1b = t1b.x*atB.x + t1b.y*atB.y + t1b.z*atB.z + t1b.w*atB.w;
    p0a += __shfl_xor(p0a,1,64); p0b += __shfl_xor(p0b,1,64); p1a += __shfl_xor(p1a,1,64); p1b += __shfl_xor(p1b,1,64);
    p0a += __shfl_xor(p0a,2,64); p0b += __shfl_xor(p0b,2,64); p1a += __shfl_xor(p1a,2,64); p1b += __shfl_xor(p1b,2,64);
    p0a += __shfl_xor(p0a,4,64); p0b += __shfl_xor(p0b,4,64); p1a += __shfl_xor(p1a,4,64); p1b += __shfl_xor(p1b,4,64);
    p0a += __shfl_xor(p0a,8,64); p0b += __shfl_xor(p0b,8,64); p1a += __shfl_xor(p1a,8,64); p1b += __shfl_xor(p1b,8,64);

    float wv0a = __expf(fminf(p0a, 60.f));
    float wv0b = __expf(fminf(p0b, 60.f));
    float wv1a = h2v ? __expf(fminf(p1a, 60.f)) : 0.f;
    float wv1b = h2v ? __expf(fminf(p1b, 60.f)) : 0.f;
    accA += wv0a * xl0a;  accA += wv1a * xl1a;  lA += wv0a + wv1a;
    accB += wv0b * xl0b;  accB += wv1b * xl1b;  lB += wv0b + wv1b;
  }
  // merge 4 groups (butterfly over xor 16, 32)
  lA += __shfl_xor(lA,16,64); lA += __shfl_xor(lA,32,64);
  lB += __shfl_xor(lB,16,64); lB += __shfl_xor(lB,32,64);
  accA.x += __shfl_xor(accA.x,16,64); accA.x += __shfl_xor(accA.x,32,64);
  accA.y += __shfl_xor(accA.y,16,64); accA.y += __shfl_xor(accA.y,32,64);
  accA.z += __shfl_xor(accA.z,16,64); accA.z += __shfl_xor(accA.z,32,64);
  accA.w += __shfl_xor(accA.w,16,64); accA.w += __shfl_xor(accA.w,32,64);
  accB.x += __shfl_xor(accB.x,16,64); accB.x += __shfl_xor(accB.x,32,64);
  accB.y += __shfl_xor(accB.y,16,64); accB.y += __shfl_xor(accB.y,32,64);
  accB.z += __shfl_xor(accB.z,16,64); accB.z += __shfl_xor(accB.z,32,64);
  accB.w += __shfl_xor(accB.w,16,64); accB.w += __shfl_xor(accB.w,32,64);

  if (lane < 14) {
    f32x4 bA = *(const f32x4*)(bias + cb);
    f32x4 bB = *(const f32x4*)(bias + cb + 56);
    f32x4 oA = accA * (1.f / (lA + 1e-16f)) + bA;
    f32x4 oB = accB * (1.f / (lB + 1e-16f)) + bB;
    if (apply_elu) {
      oA.x = oA.x > 0.f ? oA.x : (__expf(oA.x) - 1.f);
      oA.y = oA.y > 0.f ? oA.y : (__expf(oA.y) - 1.f);
      oA.z = oA.z > 0.f ? oA.z : (__expf(oA.z) - 1.f);
      oA.w = oA.w > 0.f ? oA.w : (__expf(oA.w) - 1.f);
      oB.x = oB.x > 0.f ? oB.x : (__expf(oB.x) - 1.f);
      oB.y = oB.y > 0.f ? oB.y : (__expf(oB.y) - 1.f);
      oB.z = oB.z > 0.f ? oB.z : (__expf(oB.z) - 1.f);
      oB.w = oB.w > 0.f ? oB.w : (__expf(oB.w) - 1.f);
    }
    *(f32x4*)(out + (size_t)n * HC + cb) = oA;
    *(f32x4*)(out + (size_t)n * HC + cb + 56) = oB;
  }
}

// per-channel sum / sumsq over NN rows; contiguous row chunks per block
__global__ __launch_bounds__(448) void k_bnstats(const float* __restrict__ h, float* stat) {
  int c = threadIdx.x;
  int rows_per = (NN + gridDim.x - 1) / gridDim.x;
  int r0 = blockIdx.x * rows_per, r1 = min(NN, r0 + rows_per);
  float s = 0.f, sq = 0.f;
  for (int r = r0; r < r1; r++) {
    float v = h[(size_t)r * HC + c];
    s += v; sq += v * v;
  }
  atomicAdd(&stat[c], s);
  atomicAdd(&stat[HC + c], sq);
}

// BN finalize folded in: stat holds raw sum / sumsq
__global__ void k_bnapply(const float* __restrict__ h, const float* __restrict__ stat,
                          const float* __restrict__ gam, const float* __restrict__ bet,
                          unsigned short* __restrict__ hA) {
  int i = blockIdx.x * 256 + threadIdx.x;
  if (i >= NN * HC) return;
  int c = i % HC;
  float mean = stat[c] * (1.f / NN);
  float var  = stat[HC + c] * (1.f / NN) - mean * mean;
  float sc = rsqrtf(var + 1e-5f) * gam[c];
  float sh = bet[c] - mean * sc;
  hA[i] = f2bf(h[i] * sc + sh);
}

// LDS-staged bf16 MFMA GEMM: out[M=NN,896] = A[M,448]*Bt[896,448]^T, BK=64.
// 1-D grid with XCD-aligned decode: the 7 N-blocks sharing an A-panel are
// consecutive-mod-8 (same XCD) and within one 56-block window (temporal).
__global__ __launch_bounds__(256) void k_gemm2(const unsigned short* __restrict__ A,
                                               const unsigned short* __restrict__ Bt,
                                               unsigned short* __restrict__ out) {
  __shared__ unsigned short As[128 * 64];   // [row][k], 128 B/row (lds-load order)
  __shared__ unsigned short Bs[128 * 64];
  int bid = blockIdx.x;
  int g = bid / 56, rem = bid - g * 56;
  int xs = min(8, MT - g * 8);
  int bx = g * 8 + rem % xs;
  int by = rem / xs;
  int t = threadIdx.x;
  int w = t >> 6, lane = t & 63;
  int wm = w >> 1, wn = w & 1;
  int q = lane >> 4, r = lane & 15;
  int m0 = bx * 128;
  int n0 = by * 128;

  // staging: 1024 16B-segments per matrix; thread t covers s = t + j*256.
  const unsigned short *ag[4], *bg[4];
  unsigned short *la[4], *lb[4];
  #pragma unroll
  for (int j = 0; j < 4; j++) {
    int s = t + j * 256;
    int row = s >> 3, part = s & 7;
    int ar = m0 + row; if (ar >= NN) ar = NN - 1;
    ag[j] = A + (size_t)ar * HC + part * 8;
    bg[j] = Bt + (size_t)(n0 + row) * HC + part * 8;
    la[j] = As + s * 8;
    lb[j] = Bs + s * 8;
  }

  f32x4 zero = {0.f, 0.f, 0.f, 0.f};
  f32x4 acc[4][4];
  #pragma unroll
  for (int i = 0; i < 4; i++)
    #pragma unroll
    for (int j = 0; j < 4; j++) acc[i][j] = zero;

  for (int k0 = 0; k0 < HC; k0 += 64) {
    #pragma unroll
    for (int j = 0; j < 4; j++) {
      __builtin_amdgcn_global_load_lds(
          (const __attribute__((address_space(1))) unsigned int*)(ag[j] + k0),
          (__attribute__((address_space(3))) unsigned int*)la[j], 16, 0, 0);
      __builtin_amdgcn_global_load_lds(
          (const __attribute__((address_space(1))) unsigned int*)(bg[j] + k0),
          (__attribute__((address_space(3))) unsigned int*)lb[j], 16, 0, 0);
    }
    __syncthreads();
    #pragma unroll
    for (int kk = 0; kk < 64; kk += 32) {
      bf16x8 af[4], bf[4];
      #pragma unroll
      for (int i = 0; i < 4; i++)
        af[i] = *(const bf16x8*)(As + (wm * 64 + i * 16 + r) * 64 + kk + q * 8);
      #pragma unroll
      for (int j = 0; j < 4; j++)
        bf[j] = *(const bf16x8*)(Bs + (wn * 64 + j * 16 + r) * 64 + kk + q * 8);
      #pragma unroll
      for (int i = 0; i < 4; i++)
        #pragma unroll
        for (int j = 0; j < 4; j++)
          acc[i][j] = __builtin_amdgcn_mfma_f32_16x16x32_bf16(af[i], bf[j], acc[i][j], 0, 0, 0);
    }
    __syncthreads();
  }

  #pragma unroll
  for (int i = 0; i < 4; i++) {
    int row_base = m0 + wm * 64 + i * 16 + q * 4;   // C/D: col=lane&15, row=quad*4+reg
    #pragma unroll
    for (int j = 0; j < 4; j++) {
      int col = n0 + wn * 64 + j * 16 + r;
      #pragma unroll
      for (int reg = 0; reg < 4; reg++) {
        int row = row_base + reg;
        if (row < NN) out[(size_t)row * SS + col] = f2bf(acc[i][j][reg]);
      }
    }
  }
}

// segment-sum pool over sorted batch; also counts rows per graph (thread 0)
__global__ __launch_bounds__(448) void k_pool(const float* __restrict__ h2,
                                              const int* __restrict__ batch,
                                              float* pooled, int* cnt) {
  int c = threadIdx.x;
  int rows_per = (NN + gridDim.x - 1) / gridDim.x;
  int r0 = blockIdx.x * rows_per, r1 = min(NN, r0 + rows_per);
  if (r0 >= r1) return;
  float loc = 0.f;
  int rc = 0;
  int gcur = batch[r0];
  for (int r = r0; r < r1; r++) {
    int g = batch[r];
    if (g != gcur) {
      atomicAdd(&pooled[gcur * HC + c], loc);
      if (c == 0) atomicAdd(&cnt[gcur], rc);
      loc = 0.f; rc = 0; gcur = g;
    }
    loc += h2[(size_t)r * HC + c];
    rc++;
  }
  atomicAdd(&pooled[gcur * HC + c], loc);
  if (c == 0) atomicAdd(&cnt[gcur], rc);
}

// pooled mean -> BN over 32 graphs -> logits -> log_softmax (single block)
__global__ __launch_bounds__(448) void k_final(const float* __restrict__ pooled_sum,
                                               const int* __restrict__ cnt,
                                               const float* __restrict__ gam,
                                               const float* __restrict__ bet,
                                               const float* __restrict__ Wlin,
                                               const float* __restrict__ blin,
                                               float* __restrict__ out) {
  __shared__ float P[GG * HC];
  __shared__ float L[GG * 18];
  __shared__ float red[GG];
  int c = threadIdx.x;
  float s = 0.f, sq = 0.f;
  for (int g = 0; g < GG; g++) {
    float v = pooled_sum[g * HC + c] / fmaxf((float)cnt[g], 1.f);
    P[g * HC + c] = v; s += v; sq += v * v;
  }
  float mean = s * (1.f / GG);
  float var  = sq * (1.f / GG) - mean * mean;
  float sc = rsqrtf(var + 1e-5f) * gam[c];
  float sh = bet[c] - mean * sc;
  for (int g = 0; g < GG; g++) P[g * HC + c] = P[g * HC + c] * sc + sh;
  __syncthreads();
  for (int o = c; o < GG * 18; o += HC) {
    int g = o / 18, j = o - g * 18;
    float acc = blin[j];
    for (int k = 0; k < HC; k++) acc += P[g * HC + k] * Wlin[k * 18 + j];
    L[o] = acc;
  }
  __syncthreads();
  if (c < GG) {
    float mx = -3.4e38f;
    for (int j = 0; j < 18; j++) mx = fmaxf(mx, L[c * 18 + j]);
    float se = 0.f;
    for (int j = 0; j < 18; j++) se += __expf(L[c * 18 + j] - mx);
    red[c] = mx + logf(se);
  }
  __syncthreads();
  for (int o = c; o < GG * 18; o += HC) out[o] = L[o] - red[o / 18];
}

extern "C" void kernel_launch(void* const* d_in, const int* in_sizes, int n_in,
                              void* d_out, int out_size, void* d_ws, size_t ws_size,
                              hipStream_t stream) {
  (void)in_sizes; (void)n_in; (void)out_size; (void)ws_size;
  const float* x     = (const float*)d_in[0];
  const int*   ei    = (const int*)d_in[1];
  const float* ea    = (const float*)d_in[2];
  const int*   batch = (const int*)d_in[3];
  const float* Wl1   = (const float*)d_in[4];
  const float* Wr1   = (const float*)d_in[5];
  const float* We1   = (const float*)d_in[6];
  const float* att1  = (const float*)d_in[7];
  const float* bias1 = (const float*)d_in[8];
  const float* Wl2   = (const float*)d_in[9];
  const float* Wr2   = (const float*)d_in[10];
  const float* We2   = (const float*)d_in[11];
  const float* att2  = (const float*)d_in[12];
  const float* bias2 = (const float*)d_in[13];
  const float* gam   = (const float*)d_in[14];
  const float* bet   = (const float*)d_in[15];
  const float* Wlin  = (const float*)d_in[16];
  const float* blin  = (const float*)d_in[17];
  float* out = (float*)d_out;
  const int* srcp = ei;
  const int* dstp = ei + EE;

  char* ws = (char*)d_ws;
  size_t off = 0;
  auto alloc = [&](size_t bytes) -> char* {
    char* p = ws + off;
    off = (off + bytes + 255) & ~(size_t)255;
    return p;
  };
  // zero-region: deg | bnstat | pooled | cnt (contiguous, one memset)
  int*   deg     = (int*)  alloc(NN * 4);
  float* bnstat  = (float*)alloc(HC * 2 * 4);
  float* pooled  = (float*)alloc(GG * HC * 4 + GG * 4);
  int*   cnt     = (int*)(pooled + GG * HC);
  size_t zlen    = (size_t)((char*)(cnt + GG) - (char*)deg);

  int*   offs    = (int*)  alloc((NN + 1) * 4);
  int*   cursor  = (int*)  alloc(NN * 4);
  int*   csr_src = (int*)  alloc((size_t)EN * 4);
  float* csr_ea  = (float*)alloc((size_t)EN * EAS * 4);
  unsigned short* xlr = (unsigned short*)alloc((size_t)NN * SS * 2); // bf16, reused L1/L2
  float* h1      = (float*)alloc((size_t)NN * HC * 4);   // attn out (both layers)
  unsigned short* h1A = (unsigned short*)alloc((size_t)NN * HC * 2);
  unsigned short* xb  = (unsigned short*)alloc((size_t)NN * DINN * 2);
  unsigned short* W1t = (unsigned short*)alloc((size_t)SS * DINN * 2);
  unsigned short* W2t = (unsigned short*)alloc((size_t)SS * HC * 2);

  // ---- preprocessing: CSR by dst ----
  hipMemsetAsync(deg, 0, zlen, stream);
  k_deg<<<(EE + 255) / 256, 256, 0, stream>>>(dstp, deg);
  k_scan<<<1, 1024, 0, stream>>>(deg, offs, cursor);
  k_scatter<<<(EE + 255) / 256, 256, 0, stream>>>(srcp, dstp, ea, cursor, csr_src, csr_ea);
  // self-loop attrs + all bf16 casts in one dispatch
  k_aux<<<(NN + XCN + W1N + W2N + 255) / 256, 256, 0, stream>>>(
      offs, csr_src, csr_ea, x, xb, Wl1, Wr1, W1t, Wl2, Wr2, W2t);

  // ---- layer 1 ----
  dim3 g1((NN + 63) / 64, SS / 64);
  k_gemm1<<<g1, 256, 0, stream>>>(xb, W1t, xlr);
  k_attn<<<NN, 256, 0, stream>>>(xlr, offs, csr_src, csr_ea, We1, att1, bias1, h1, 1);
  // ---- BN ----
  k_bnstats<<<256, HC, 0, stream>>>(h1, bnstat);
  k_bnapply<<<(NN * HC + 255) / 256, 256, 0, stream>>>(h1, bnstat, gam, bet, h1A);

  // ---- layer 2 ----
  k_gemm2<<<MT * NT, 256, 0, stream>>>(h1A, W2t, xlr);
  k_attn<<<NN, 256, 0, stream>>>(xlr, offs, csr_src, csr_ea, We2, att2, bias2, h1, 0);

  // ---- pool + final ----
  k_pool<<<640, HC, 0, stream>>>(h1, batch, pooled, cnt);
  k_final<<<1, HC, 0, stream>>>(pooled, cnt, gam, bet, Wlin, blin, out);
}

// Round 8
// 492.714 us; speedup vs baseline: 2.7211x; 1.1081x over previous
//
#include <hip/hip_runtime.h>
#include <hip/hip_bf16.h>

#define NN   20000
#define EE   320000
#define EN   340000   // EE + NN (self loops)
#define HH   8
#define CC   56
#define HC   448
#define SS   896      // fused xl|xr stride
#define DEA  5
#define EAS  8        // padded csr_ea stride (floats)
#define DINN 32
#define GG   32
#define NEG  0.2f

#define MT   157      // gemm2 M-tiles (ceil(20000/128))
#define NT   7        // gemm2 N-tiles (896/128)

typedef short bf16x8 __attribute__((ext_vector_type(8)));
typedef float f32x4  __attribute__((ext_vector_type(4)));

static __device__ __forceinline__ unsigned short f2bf(float f) {
  unsigned int u = __float_as_uint(f);
  u += 0x7fffu + ((u >> 16) & 1u);   // round-to-nearest-even
  return (unsigned short)(u >> 16);
}

static __device__ __forceinline__ f32x4 bf4_to_f32x4(uint2 r) {
  f32x4 o;
  o.x = __uint_as_float(r.x << 16);
  o.y = __uint_as_float(r.x & 0xffff0000u);
  o.z = __uint_as_float(r.y << 16);
  o.w = __uint_as_float(r.y & 0xffff0000u);
  return o;
}

__global__ void k_deg(const int* __restrict__ dst, int* deg) {
  int e = blockIdx.x * 256 + threadIdx.x;
  if (e < EE) atomicAdd(&deg[dst[e]], 1);
}

// exclusive scan of (deg[n]+1) -> offs[0..NN] and cursor[0..NN-1]
__global__ __launch_bounds__(1024) void k_scan(const int* __restrict__ deg, int* offs,
                                               int* cursor) {
  __shared__ int tot[1024];
  int t = threadIdx.x;
  int base = t * 20;
  int loc[20];
  int s = 0;
  #pragma unroll
  for (int i = 0; i < 20; i++) {
    int idx = base + i;
    int v = (idx < NN) ? deg[idx] + 1 : 0;
    loc[i] = s;           // thread-local exclusive prefix
    s += v;
  }
  tot[t] = s;
  __syncthreads();
  for (int o = 1; o < 1024; o <<= 1) {
    int v = (t >= o) ? tot[t - o] : 0;
    __syncthreads();
    tot[t] += v;
    __syncthreads();
  }
  int basesum = (t == 0) ? 0 : tot[t - 1];
  #pragma unroll
  for (int i = 0; i < 20; i++) {
    int idx = base + i;
    if (idx < NN) { offs[idx] = basesum + loc[i]; cursor[idx] = basesum + loc[i]; }
  }
  if (t == 1023) offs[NN] = tot[1023];
}

// scatter real edges; slots [offs[n], offs[n+1]-1) — last slot reserved for self-loop
__global__ void k_scatter(const int* __restrict__ src, const int* __restrict__ dst,
                          const float* __restrict__ ea,
                          int* cursor, int* __restrict__ csr_src, float* __restrict__ csr_ea) {
  int i = blockIdx.x * 256 + threadIdx.x;
  if (i >= EE) return;
  int d = dst[i], s = src[i];
  float a[DEA];
  #pragma unroll
  for (int j = 0; j < DEA; j++) a[j] = ea[(size_t)i * DEA + j];
  int pos = atomicAdd(&cursor[d], 1);
  csr_src[pos] = s;
  float* o = csr_ea + (size_t)pos * EAS;
  #pragma unroll
  for (int j = 0; j < DEA; j++) o[j] = a[j];
}

// fused: self-loop attrs + x->bf16 cast + W1t/W2t transposed bf16 casts
// (W reads coalesced: consecutive threads -> consecutive W columns; writes scattered)
#define XCN (NN * DINN)
#define W1N (SS * DINN)
#define W2N (SS * HC)
__global__ void k_aux(const int* __restrict__ offs,
                      int* __restrict__ csr_src, float* __restrict__ csr_ea,
                      const float* __restrict__ x, unsigned short* __restrict__ xb,
                      const float* __restrict__ Wl1, const float* __restrict__ Wr1,
                      unsigned short* __restrict__ W1t,
                      const float* __restrict__ Wl2, const float* __restrict__ Wr2,
                      unsigned short* __restrict__ W2t) {
  int i = blockIdx.x * 256 + threadIdx.x;
  if (i < NN) {
    int n = i;
    int e0 = offs[n], e1 = offs[n + 1] - 1;   // real edges in [e0, e1)
    float a0 = 0.f, a1 = 0.f, a2 = 0.f, a3 = 0.f, a4 = 0.f;
    for (int e = e0; e < e1; e++) {
      const float* p = csr_ea + (size_t)e * EAS;
      a0 += p[0]; a1 += p[1]; a2 += p[2]; a3 += p[3]; a4 += p[4];
    }
    float inv = 1.f / fmaxf((float)(e1 - e0), 1.f);
    csr_src[e1] = n;
    float* o = csr_ea + (size_t)e1 * EAS;
    o[0] = a0 * inv; o[1] = a1 * inv; o[2] = a2 * inv; o[3] = a3 * inv; o[4] = a4 * inv;
    return;
  }
  i -= NN;
  if (i < XCN) { xb[i] = f2bf(x[i]); return; }
  i -= XCN;
  if (i < W1N) {
    int k = i / SS, col = i - k * SS;       // coalesced read over col
    int cc = (col < HC) ? col : col - HC;
    const float* W = (col < HC) ? Wl1 : Wr1;
    W1t[(size_t)col * DINN + k] = f2bf(W[(size_t)k * HC + cc]);
    return;
  }
  i -= W1N;
  if (i < W2N) {
    int k = i / SS, col = i - k * SS;       // coalesced read over col
    int cc = (col < HC) ? col : col - HC;
    const float* W = (col < HC) ? Wl2 : Wr2;
    W2t[(size_t)col * HC + k] = f2bf(W[(size_t)k * HC + cc]);
  }
}

// MFMA gemm1: out[NN,896] = xb[NN,32] @ W1t[896,32]^T, bf16 out. One K-step.
__global__ __launch_bounds__(256) void k_gemm1(const unsigned short* __restrict__ xb,
                                               const unsigned short* __restrict__ W1t,
                                               unsigned short* __restrict__ out) {
  int w = threadIdx.x >> 6, lane = threadIdx.x & 63;
  int q = lane >> 4, r = lane & 15;
  int m0 = (blockIdx.x * 4 + w) * 16;
  int n0 = blockIdx.y * 64;
  int arow = m0 + r; if (arow >= NN) arow = NN - 1;
  bf16x8 a = *(const bf16x8*)(xb + (size_t)arow * DINN + q * 8);
  #pragma unroll
  for (int j = 0; j < 4; j++) {
    bf16x8 b = *(const bf16x8*)(W1t + (size_t)(n0 + j * 16 + r) * DINN + q * 8);
    f32x4 acc = {0.f, 0.f, 0.f, 0.f};
    acc = __builtin_amdgcn_mfma_f32_16x16x32_bf16(a, b, acc, 0, 0, 0);
    #pragma unroll
    for (int reg = 0; reg < 4; reg++) {
      int row = m0 + q * 4 + reg;         // C/D: col=lane&15, row=quad*4+reg
      if (row < NN) out[(size_t)row * SS + n0 + j * 16 + r] = f2bf(acc[reg]);
    }
  }
}

// Fused GATv2 attention v5: wave = (node, head-pair hp). Group = 32 lanes =
// 1 edge x 2 heads (lanes 0-15: head 2hp ch, 16-31: head 2hp+1 ch); each lane
// owns ONE head's 4 channels -> single {xr,att,w[5]} set (low VGPR). 2 groups
// per wave, 2x edge unroll (4 gathers in flight). Score reduce = xor{1,2,4,8}
// within 16-half; group merge = xor 32.
__global__ __launch_bounds__(256) void k_attn(
    const unsigned short* __restrict__ xlr,
    const int* __restrict__ offs, const int* __restrict__ csr_src,
    const float* __restrict__ csr_ea,
    const float* __restrict__ We, const float* __restrict__ att,
    const float* __restrict__ bias, float* __restrict__ out, int apply_elu) {
  int wid = (blockIdx.x << 2) + (threadIdx.x >> 6);
  int n = wid >> 2;
  if (n >= NN) return;
  int hp = wid & 3;              // heads 2hp, 2hp+1
  int lane = threadIdx.x & 63;
  int grp  = lane >> 5;          // edge group (0,1)
  int gl   = lane & 31;
  int hd   = gl >> 4;            // head within pair
  int sub  = gl & 15;
  bool cvalid = sub < 14;
  int cj = cvalid ? sub : 13;
  int cb = hp * 112 + hd * 56 + cj * 4;   // this lane's 4-channel base

  f32x4 xr4 = bf4_to_f32x4(*(const uint2*)(xlr + (size_t)n * SS + HC + cb));
  f32x4 at4 = *(const f32x4*)(att + cb);
  if (!cvalid) at4 = (f32x4){0.f, 0.f, 0.f, 0.f};
  f32x4 w0 = *(const f32x4*)(We + 0 * HC + cb);
  f32x4 w1 = *(const f32x4*)(We + 1 * HC + cb);
  f32x4 w2 = *(const f32x4*)(We + 2 * HC + cb);
  f32x4 w3 = *(const f32x4*)(We + 3 * HC + cb);
  f32x4 w4 = *(const f32x4*)(We + 4 * HC + cb);

  int e0 = offs[n], e1 = offs[n + 1];
  float l = 0.f;
  f32x4 acc = {0.f, 0.f, 0.f, 0.f};

  for (int e = e0 + grp; e < e1; e += 4) {
    int eb = e + 2;
    bool h2v = eb < e1;
    int ebc = h2v ? eb : e;
    int s0 = csr_src[e];
    int s1 = csr_src[ebc];
    const float* ep0 = csr_ea + (size_t)e * EAS;
    const float* ep1 = csr_ea + (size_t)ebc * EAS;
    f32x4 ea0 = *(const f32x4*)ep0;  float e40 = ep0[4];
    f32x4 ea1 = *(const f32x4*)ep1;  float e41 = ep1[4];
    uint2 r0 = *(const uint2*)(xlr + (size_t)s0 * SS + cb);
    uint2 r1 = *(const uint2*)(xlr + (size_t)s1 * SS + cb);
    f32x4 xl0 = bf4_to_f32x4(r0);
    f32x4 xl1 = bf4_to_f32x4(r1);

    f32x4 t0 = xl0 + xr4;
    t0 += ea0.x * w0; t0 += ea0.y * w1; t0 += ea0.z * w2; t0 += ea0.w * w3; t0 += e40 * w4;
    f32x4 t1 = xl1 + xr4;
    t1 += ea1.x * w0; t1 += ea1.y * w1; t1 += ea1.z * w2; t1 += ea1.w * w3; t1 += e41 * w4;
    t0.x = fmaxf(t0.x, NEG * t0.x); t0.y = fmaxf(t0.y, NEG * t0.y);
    t0.z = fmaxf(t0.z, NEG * t0.z); t0.w = fmaxf(t0.w, NEG * t0.w);
    t1.x = fmaxf(t1.x, NEG * t1.x); t1.y = fmaxf(t1.y, NEG * t1.y);
    t1.z = fmaxf(t1.z, NEG * t1.z); t1.w = fmaxf(t1.w, NEG * t1.w);
    float p0 = t0.x * at4.x + t0.y * at4.y + t0.z * at4.z + t0.w * at4.w;
    float p1 = t1.x * at4.x + t1.y * at4.y + t1.z * at4.z + t1.w * at4.w;
    p0 += __shfl_xor(p0, 1, 64);  p1 += __shfl_xor(p1, 1, 64);
    p0 += __shfl_xor(p0, 2, 64);  p1 += __shfl_xor(p1, 2, 64);
    p0 += __shfl_xor(p0, 4, 64);  p1 += __shfl_xor(p1, 4, 64);
    p0 += __shfl_xor(p0, 8, 64);  p1 += __shfl_xor(p1, 8, 64);
    float wv0 = __expf(fminf(p0, 60.f));
    float wv1 = h2v ? __expf(fminf(p1, 60.f)) : 0.f;
    acc += wv0 * xl0;
    acc += wv1 * xl1;
    l += wv0 + wv1;
  }
  // merge the 2 edge groups (xor 32)
  l += __shfl_xor(l, 32, 64);
  acc.x += __shfl_xor(acc.x, 32, 64);
  acc.y += __shfl_xor(acc.y, 32, 64);
  acc.z += __shfl_xor(acc.z, 32, 64);
  acc.w += __shfl_xor(acc.w, 32, 64);

  if (lane < 32 && sub < 14) {
    f32x4 b4 = *(const f32x4*)(bias + cb);
    f32x4 o = acc * (1.f / (l + 1e-16f)) + b4;
    if (apply_elu) {
      o.x = o.x > 0.f ? o.x : (__expf(o.x) - 1.f);
      o.y = o.y > 0.f ? o.y : (__expf(o.y) - 1.f);
      o.z = o.z > 0.f ? o.z : (__expf(o.z) - 1.f);
      o.w = o.w > 0.f ? o.w : (__expf(o.w) - 1.f);
    }
    *(f32x4*)(out + (size_t)n * HC + cb) = o;
  }
}

// per-channel sum / sumsq over NN rows; contiguous row chunks per block
__global__ __launch_bounds__(448) void k_bnstats(const float* __restrict__ h, float* stat) {
  int c = threadIdx.x;
  int rows_per = (NN + gridDim.x - 1) / gridDim.x;
  int r0 = blockIdx.x * rows_per, r1 = min(NN, r0 + rows_per);
  float s = 0.f, sq = 0.f;
  for (int r = r0; r < r1; r++) {
    float v = h[(size_t)r * HC + c];
    s += v; sq += v * v;
  }
  atomicAdd(&stat[c], s);
  atomicAdd(&stat[HC + c], sq);
}

// BN finalize folded in: stat holds raw sum / sumsq
__global__ void k_bnapply(const float* __restrict__ h, const float* __restrict__ stat,
                          const float* __restrict__ gam, const float* __restrict__ bet,
                          unsigned short* __restrict__ hA) {
  int i = blockIdx.x * 256 + threadIdx.x;
  if (i >= NN * HC) return;
  int c = i % HC;
  float mean = stat[c] * (1.f / NN);
  float var  = stat[HC + c] * (1.f / NN) - mean * mean;
  float sc = rsqrtf(var + 1e-5f) * gam[c];
  float sh = bet[c] - mean * sc;
  hA[i] = f2bf(h[i] * sc + sh);
}

// LDS-staged bf16 MFMA GEMM: out[M=NN,896] = A[M,448]*Bt[896,448]^T, BK=64.
// 1-D grid with XCD-aligned decode: the 7 N-blocks sharing an A-panel are
// consecutive-mod-8 (same XCD) and within one 56-block window (temporal).
__global__ __launch_bounds__(256) void k_gemm2(const unsigned short* __restrict__ A,
                                               const unsigned short* __restrict__ Bt,
                                               unsigned short* __restrict__ out) {
  __shared__ unsigned short As[128 * 64];   // [row][k], 128 B/row (lds-load order)
  __shared__ unsigned short Bs[128 * 64];
  int bid = blockIdx.x;
  int g = bid / 56, rem = bid - g * 56;
  int xs = min(8, MT - g * 8);
  int bx = g * 8 + rem % xs;
  int by = rem / xs;
  int t = threadIdx.x;
  int w = t >> 6, lane = t & 63;
  int wm = w >> 1, wn = w & 1;
  int q = lane >> 4, r = lane & 15;
  int m0 = bx * 128;
  int n0 = by * 128;

  // staging: 1024 16B-segments per matrix; thread t covers s = t + j*256.
  const unsigned short *ag[4], *bg[4];
  unsigned short *la[4], *lb[4];
  #pragma unroll
  for (int j = 0; j < 4; j++) {
    int s = t + j * 256;
    int row = s >> 3, part = s & 7;
    int ar = m0 + row; if (ar >= NN) ar = NN - 1;
    ag[j] = A + (size_t)ar * HC + part * 8;
    bg[j] = Bt + (size_t)(n0 + row) * HC + part * 8;
    la[j] = As + s * 8;
    lb[j] = Bs + s * 8;
  }

  f32x4 zero = {0.f, 0.f, 0.f, 0.f};
  f32x4 acc[4][4];
  #pragma unroll
  for (int i = 0; i < 4; i++)
    #pragma unroll
    for (int j = 0; j < 4; j++) acc[i][j] = zero;

  for (int k0 = 0; k0 < HC; k0 += 64) {
    #pragma unroll
    for (int j = 0; j < 4; j++) {
      __builtin_amdgcn_global_load_lds(
          (const __attribute__((address_space(1))) unsigned int*)(ag[j] + k0),
          (__attribute__((address_space(3))) unsigned int*)la[j], 16, 0, 0);
      __builtin_amdgcn_global_load_lds(
          (const __attribute__((address_space(1))) unsigned int*)(bg[j] + k0),
          (__attribute__((address_space(3))) unsigned int*)lb[j], 16, 0, 0);
    }
    __syncthreads();
    #pragma unroll
    for (int kk = 0; kk < 64; kk += 32) {
      bf16x8 af[4], bf[4];
      #pragma unroll
      for (int i = 0; i < 4; i++)
        af[i] = *(const bf16x8*)(As + (wm * 64 + i * 16 + r) * 64 + kk + q * 8);
      #pragma unroll
      for (int j = 0; j < 4; j++)
        bf[j] = *(const bf16x8*)(Bs + (wn * 64 + j * 16 + r) * 64 + kk + q * 8);
      #pragma unroll
      for (int i = 0; i < 4; i++)
        #pragma unroll
        for (int j = 0; j < 4; j++)
          acc[i][j] = __builtin_amdgcn_mfma_f32_16x16x32_bf16(af[i], bf[j], acc[i][j], 0, 0, 0);
    }
    __syncthreads();
  }

  #pragma unroll
  for (int i = 0; i < 4; i++) {
    int row_base = m0 + wm * 64 + i * 16 + q * 4;   // C/D: col=lane&15, row=quad*4+reg
    #pragma unroll
    for (int j = 0; j < 4; j++) {
      int col = n0 + wn * 64 + j * 16 + r;
      #pragma unroll
      for (int reg = 0; reg < 4; reg++) {
        int row = row_base + reg;
        if (row < NN) out[(size_t)row * SS + col] = f2bf(acc[i][j][reg]);
      }
    }
  }
}

// segment-sum pool over sorted batch; also counts rows per graph (thread 0)
__global__ __launch_bounds__(448) void k_pool(const float* __restrict__ h2,
                                              const int* __restrict__ batch,
                                              float* pooled, int* cnt) {
  int c = threadIdx.x;
  int rows_per = (NN + gridDim.x - 1) / gridDim.x;
  int r0 = blockIdx.x * rows_per, r1 = min(NN, r0 + rows_per);
  if (r0 >= r1) return;
  float loc = 0.f;
  int rc = 0;
  int gcur = batch[r0];
  for (int r = r0; r < r1; r++) {
    int g = batch[r];
    if (g != gcur) {
      atomicAdd(&pooled[gcur * HC + c], loc);
      if (c == 0) atomicAdd(&cnt[gcur], rc);
      loc = 0.f; rc = 0; gcur = g;
    }
    loc += h2[(size_t)r * HC + c];
    rc++;
  }
  atomicAdd(&pooled[gcur * HC + c], loc);
  if (c == 0) atomicAdd(&cnt[gcur], rc);
}

// pooled mean -> BN over 32 graphs -> logits -> log_softmax (single block)
__global__ __launch_bounds__(448) void k_final(const float* __restrict__ pooled_sum,
                                               const int* __restrict__ cnt,
                                               const float* __restrict__ gam,
                                               const float* __restrict__ bet,
                                               const float* __restrict__ Wlin,
                                               const float* __restrict__ blin,
                                               float* __restrict__ out) {
  __shared__ float P[GG * HC];
  __shared__ float L[GG * 18];
  __shared__ float red[GG];
  int c = threadIdx.x;
  float s = 0.f, sq = 0.f;
  for (int g = 0; g < GG; g++) {
    float v = pooled_sum[g * HC + c] / fmaxf((float)cnt[g], 1.f);
    P[g * HC + c] = v; s += v; sq += v * v;
  }
  float mean = s * (1.f / GG);
  float var  = sq * (1.f / GG) - mean * mean;
  float sc = rsqrtf(var + 1e-5f) * gam[c];
  float sh = bet[c] - mean * sc;
  for (int g = 0; g < GG; g++) P[g * HC + c] = P[g * HC + c] * sc + sh;
  __syncthreads();
  for (int o = c; o < GG * 18; o += HC) {
    int g = o / 18, j = o - g * 18;
    float acc = blin[j];
    for (int k = 0; k < HC; k++) acc += P[g * HC + k] * Wlin[k * 18 + j];
    L[o] = acc;
  }
  __syncthreads();
  if (c < GG) {
    float mx = -3.4e38f;
    for (int j = 0; j < 18; j++) mx = fmaxf(mx, L[c * 18 + j]);
    float se = 0.f;
    for (int j = 0; j < 18; j++) se += __expf(L[c * 18 + j] - mx);
    red[c] = mx + logf(se);
  }
  __syncthreads();
  for (int o = c; o < GG * 18; o += HC) out[o] = L[o] - red[o / 18];
}

extern "C" void kernel_launch(void* const* d_in, const int* in_sizes, int n_in,
                              void* d_out, int out_size, void* d_ws, size_t ws_size,
                              hipStream_t stream) {
  (void)in_sizes; (void)n_in; (void)out_size; (void)ws_size;
  const float* x     = (const float*)d_in[0];
  const int*   ei    = (const int*)d_in[1];
  const float* ea    = (const float*)d_in[2];
  const int*   batch = (const int*)d_in[3];
  const float* Wl1   = (const float*)d_in[4];
  const float* Wr1   = (const float*)d_in[5];
  const float* We1   = (const float*)d_in[6];
  const float* att1  = (const float*)d_in[7];
  const float* bias1 = (const float*)d_in[8];
  const float* Wl2   = (const float*)d_in[9];
  const float* Wr2   = (const float*)d_in[10];
  const float* We2   = (const float*)d_in[11];
  const float* att2  = (const float*)d_in[12];
  const float* bias2 = (const float*)d_in[13];
  const float* gam   = (const float*)d_in[14];
  const float* bet   = (const float*)d_in[15];
  const float* Wlin  = (const float*)d_in[16];
  const float* blin  = (const float*)d_in[17];
  float* out = (float*)d_out;
  const int* srcp = ei;
  const int* dstp = ei + EE;

  char* ws = (char*)d_ws;
  size_t off = 0;
  auto alloc = [&](size_t bytes) -> char* {
    char* p = ws + off;
    off = (off + bytes + 255) & ~(size_t)255;
    return p;
  };
  // zero-region: deg | bnstat | pooled | cnt (contiguous, one memset)
  int*   deg     = (int*)  alloc(NN * 4);
  float* bnstat  = (float*)alloc(HC * 2 * 4);
  float* pooled  = (float*)alloc(GG * HC * 4 + GG * 4);
  int*   cnt     = (int*)(pooled + GG * HC);
  size_t zlen    = (size_t)((char*)(cnt + GG) - (char*)deg);

  int*   offs    = (int*)  alloc((NN + 1) * 4);
  int*   cursor  = (int*)  alloc(NN * 4);
  int*   csr_src = (int*)  alloc((size_t)EN * 4);
  float* csr_ea  = (float*)alloc((size_t)EN * EAS * 4);
  unsigned short* xlr = (unsigned short*)alloc((size_t)NN * SS * 2); // bf16, reused L1/L2
  float* h1      = (float*)alloc((size_t)NN * HC * 4);   // attn out (both layers)
  unsigned short* h1A = (unsigned short*)alloc((size_t)NN * HC * 2);
  unsigned short* xb  = (unsigned short*)alloc((size_t)NN * DINN * 2);
  unsigned short* W1t = (unsigned short*)alloc((size_t)SS * DINN * 2);
  unsigned short* W2t = (unsigned short*)alloc((size_t)SS * HC * 2);

  // ---- preprocessing: CSR by dst ----
  hipMemsetAsync(deg, 0, zlen, stream);
  k_deg<<<(EE + 255) / 256, 256, 0, stream>>>(dstp, deg);
  k_scan<<<1, 1024, 0, stream>>>(deg, offs, cursor);
  k_scatter<<<(EE + 255) / 256, 256, 0, stream>>>(srcp, dstp, ea, cursor, csr_src, csr_ea);
  // self-loop attrs + all bf16 casts in one dispatch
  k_aux<<<(NN + XCN + W1N + W2N + 255) / 256, 256, 0, stream>>>(
      offs, csr_src, csr_ea, x, xb, Wl1, Wr1, W1t, Wl2, Wr2, W2t);

  // ---- layer 1 ----
  dim3 g1((NN + 63) / 64, SS / 64);
  k_gemm1<<<g1, 256, 0, stream>>>(xb, W1t, xlr);
  k_attn<<<NN, 256, 0, stream>>>(xlr, offs, csr_src, csr_ea, We1, att1, bias1, h1, 1);
  // ---- BN ----
  k_bnstats<<<256, HC, 0, stream>>>(h1, bnstat);
  k_bnapply<<<(NN * HC + 255) / 256, 256, 0, stream>>>(h1, bnstat, gam, bet, h1A);

  // ---- layer 2 ----
  k_gemm2<<<MT * NT, 256, 0, stream>>>(h1A, W2t, xlr);
  k_attn<<<NN, 256, 0, stream>>>(xlr, offs, csr_src, csr_ea, We2, att2, bias2, h1, 0);

  // ---- pool + final ----
  k_pool<<<640, HC, 0, stream>>>(h1, batch, pooled, cnt);
  k_final<<<1, HC, 0, stream>>>(pooled, cnt, gam, bet, Wlin, blin, out);
}

// Round 9
// 473.921 us; speedup vs baseline: 2.8290x; 1.0397x over previous
//
#include <hip/hip_runtime.h>
#include <hip/hip_bf16.h>

#define NN   20000
#define EE   320000
#define EN   340000   // EE + NN (self loops)
#define HH   8
#define CC   56
#define HC   448
#define DEA  5
#define EAS  8        // padded csr_ea stride (floats)
#define DINN 32
#define GG   32
#define NEG  0.2f

#define PS   512      // padded per-half channel count (8 heads x 64)
#define PSS  1024     // padded xl|xr row stride
#define MT   157      // gemm2 M-tiles (ceil(20000/128))
#define NT   7        // gemm2 N-tiles (896/128)
#define SS   896      // real xl|xr col count

typedef short bf16x8 __attribute__((ext_vector_type(8)));
typedef float f32x4  __attribute__((ext_vector_type(4)));
typedef float f32x8  __attribute__((ext_vector_type(8)));

static __device__ __forceinline__ unsigned short f2bf(float f) {
  unsigned int u = __float_as_uint(f);
  u += 0x7fffu + ((u >> 16) & 1u);   // round-to-nearest-even
  return (unsigned short)(u >> 16);
}

static __device__ __forceinline__ f32x8 bf8_to_f32x8(uint4 u) {
  f32x8 o;
  o[0] = __uint_as_float(u.x << 16); o[1] = __uint_as_float(u.x & 0xffff0000u);
  o[2] = __uint_as_float(u.y << 16); o[3] = __uint_as_float(u.y & 0xffff0000u);
  o[4] = __uint_as_float(u.z << 16); o[5] = __uint_as_float(u.z & 0xffff0000u);
  o[6] = __uint_as_float(u.w << 16); o[7] = __uint_as_float(u.w & 0xffff0000u);
  return o;
}

__global__ void k_deg(const int* __restrict__ dst, int* deg) {
  int e = blockIdx.x * 256 + threadIdx.x;
  if (e < EE) atomicAdd(&deg[dst[e]], 1);
}

// exclusive scan of (deg[n]+1) -> offs[0..NN] and cursor[0..NN-1]
__global__ __launch_bounds__(1024) void k_scan(const int* __restrict__ deg, int* offs,
                                               int* cursor) {
  __shared__ int tot[1024];
  int t = threadIdx.x;
  int base = t * 20;
  int loc[20];
  int s = 0;
  #pragma unroll
  for (int i = 0; i < 20; i++) {
    int idx = base + i;
    int v = (idx < NN) ? deg[idx] + 1 : 0;
    loc[i] = s;
    s += v;
  }
  tot[t] = s;
  __syncthreads();
  for (int o = 1; o < 1024; o <<= 1) {
    int v = (t >= o) ? tot[t - o] : 0;
    __syncthreads();
    tot[t] += v;
    __syncthreads();
  }
  int basesum = (t == 0) ? 0 : tot[t - 1];
  #pragma unroll
  for (int i = 0; i < 20; i++) {
    int idx = base + i;
    if (idx < NN) { offs[idx] = basesum + loc[i]; cursor[idx] = basesum + loc[i]; }
  }
  if (t == 1023) offs[NN] = tot[1023];
}

// scatter real edges; slots [offs[n], offs[n+1]-1) — last slot reserved for self-loop
__global__ void k_scatter(const int* __restrict__ src, const int* __restrict__ dst,
                          const float* __restrict__ ea,
                          int* cursor, int* __restrict__ csr_src, float* __restrict__ csr_ea) {
  int i = blockIdx.x * 256 + threadIdx.x;
  if (i >= EE) return;
  int d = dst[i], s = src[i];
  float a[DEA];
  #pragma unroll
  for (int j = 0; j < DEA; j++) a[j] = ea[(size_t)i * DEA + j];
  int pos = atomicAdd(&cursor[d], 1);
  csr_src[pos] = s;
  float* o = csr_ea + (size_t)pos * EAS;
  #pragma unroll
  for (int j = 0; j < DEA; j++) o[j] = a[j];
}

// fused: self-loop attrs + x->bf16 cast + W1t/W2t transposed bf16 casts
#define XCN (NN * DINN)
#define W1N (SS * DINN)
#define W2N (SS * HC)
__global__ void k_aux(const int* __restrict__ offs,
                      int* __restrict__ csr_src, float* __restrict__ csr_ea,
                      const float* __restrict__ x, unsigned short* __restrict__ xb,
                      const float* __restrict__ Wl1, const float* __restrict__ Wr1,
                      unsigned short* __restrict__ W1t,
                      const float* __restrict__ Wl2, const float* __restrict__ Wr2,
                      unsigned short* __restrict__ W2t) {
  int i = blockIdx.x * 256 + threadIdx.x;
  if (i < NN) {
    int n = i;
    int e0 = offs[n], e1 = offs[n + 1] - 1;
    float a0 = 0.f, a1 = 0.f, a2 = 0.f, a3 = 0.f, a4 = 0.f;
    for (int e = e0; e < e1; e++) {
      const float* p = csr_ea + (size_t)e * EAS;
      a0 += p[0]; a1 += p[1]; a2 += p[2]; a3 += p[3]; a4 += p[4];
    }
    float inv = 1.f / fmaxf((float)(e1 - e0), 1.f);
    csr_src[e1] = n;
    float* o = csr_ea + (size_t)e1 * EAS;
    o[0] = a0 * inv; o[1] = a1 * inv; o[2] = a2 * inv; o[3] = a3 * inv; o[4] = a4 * inv;
    return;
  }
  i -= NN;
  if (i < XCN) { xb[i] = f2bf(x[i]); return; }
  i -= XCN;
  if (i < W1N) {
    int k = i / SS, col = i - k * SS;
    int cc = (col < HC) ? col : col - HC;
    const float* W = (col < HC) ? Wl1 : Wr1;
    W1t[(size_t)col * DINN + k] = f2bf(W[(size_t)k * HC + cc]);
    return;
  }
  i -= W1N;
  if (i < W2N) {
    int k = i / SS, col = i - k * SS;
    int cc = (col < HC) ? col : col - HC;
    const float* W = (col < HC) ? Wl2 : Wr2;
    W2t[(size_t)col * HC + k] = f2bf(W[(size_t)k * HC + cc]);
  }
}

// MFMA gemm1: xlr[NN,1024 padded] = xb[NN,32] @ W1t[896,32]^T, bf16. One K-step.
__global__ __launch_bounds__(256) void k_gemm1(const unsigned short* __restrict__ xb,
                                               const unsigned short* __restrict__ W1t,
                                               unsigned short* __restrict__ out) {
  int w = threadIdx.x >> 6, lane = threadIdx.x & 63;
  int q = lane >> 4, r = lane & 15;
  int m0 = (blockIdx.x * 4 + w) * 16;
  int n0 = blockIdx.y * 64;
  int arow = m0 + r; if (arow >= NN) arow = NN - 1;
  bf16x8 a = *(const bf16x8*)(xb + (size_t)arow * DINN + q * 8);
  #pragma unroll
  for (int j = 0; j < 4; j++) {
    bf16x8 b = *(const bf16x8*)(W1t + (size_t)(n0 + j * 16 + r) * DINN + q * 8);
    f32x4 acc = {0.f, 0.f, 0.f, 0.f};
    acc = __builtin_amdgcn_mfma_f32_16x16x32_bf16(a, b, acc, 0, 0, 0);
    int col = n0 + j * 16 + r;
    int cp = col + 8 * (col / 56);        // padded column
    #pragma unroll
    for (int reg = 0; reg < 4; reg++) {
      int row = m0 + q * 4 + reg;         // C/D: col=lane&15, row=quad*4+reg
      if (row < NN) out[(size_t)row * PSS + cp] = f2bf(acc[reg]);
    }
  }
}

// Fused GATv2 attention v6: wave = one node, ALL 8 heads. lane = (head=lane>>3,
// sub=lane&7) covering 8 channels (16B bf16 load from padded xlr). Score reduce
// = xor{1,2,4} in the 8-lane cluster; wv uniform in-cluster, no final butterfly.
// 2x edge unroll. Layer1 -> bf16 padded outb (+ELU); Layer2 -> fp32 outf.
__global__ __launch_bounds__(256) void k_attn(
    const unsigned short* __restrict__ xlr,
    const int* __restrict__ offs, const int* __restrict__ csr_src,
    const float* __restrict__ csr_ea,
    const float* __restrict__ We, const float* __restrict__ att,
    const float* __restrict__ bias,
    unsigned short* __restrict__ outb, float* __restrict__ outf, int layer1) {
  int n = blockIdx.x * 4 + (threadIdx.x >> 6);
  if (n >= NN) return;
  int lane = threadIdx.x & 63;
  int head = lane >> 3, sub = lane & 7;
  bool v = sub < 7;                      // sub 7 = pad channels
  int pc = head * 64 + sub * 8;          // padded channel base
  int cr = head * 56 + (v ? sub : 6) * 8; // real channel base (clamped)

  f32x8 z = {0.f,0.f,0.f,0.f,0.f,0.f,0.f,0.f};
  f32x8 xr = bf8_to_f32x8(*(const uint4*)(xlr + (size_t)n * PSS + PS + pc));
  f32x8 at = *(const f32x8*)(att + cr);
  if (!v) at = z;
  f32x8 w0 = *(const f32x8*)(We + 0 * HC + cr);
  f32x8 w1 = *(const f32x8*)(We + 1 * HC + cr);
  f32x8 w2 = *(const f32x8*)(We + 2 * HC + cr);
  f32x8 w3 = *(const f32x8*)(We + 3 * HC + cr);
  f32x8 w4 = *(const f32x8*)(We + 4 * HC + cr);

  int e0 = offs[n], e1 = offs[n + 1];
  float l = 0.f;
  f32x8 acc = z;

  for (int e = e0; e < e1; e += 2) {
    int eb = e + 1;
    bool h2v = eb < e1;
    int ebc = h2v ? eb : e;
    int s0 = csr_src[e];
    int s1 = csr_src[ebc];
    const float* ep0 = csr_ea + (size_t)e * EAS;
    const float* ep1 = csr_ea + (size_t)ebc * EAS;
    f32x4 ea0 = *(const f32x4*)ep0;  float e40 = ep0[4];
    f32x4 ea1 = *(const f32x4*)ep1;  float e41 = ep1[4];
    uint4 g0 = *(const uint4*)(xlr + (size_t)s0 * PSS + pc);
    uint4 g1 = *(const uint4*)(xlr + (size_t)s1 * PSS + pc);
    f32x8 xl0 = bf8_to_f32x8(g0);
    f32x8 xl1 = bf8_to_f32x8(g1);

    f32x8 t0 = xl0 + xr;
    t0 += ea0.x * w0; t0 += ea0.y * w1; t0 += ea0.z * w2; t0 += ea0.w * w3; t0 += e40 * w4;
    f32x8 t1 = xl1 + xr;
    t1 += ea1.x * w0; t1 += ea1.y * w1; t1 += ea1.z * w2; t1 += ea1.w * w3; t1 += e41 * w4;
    #pragma unroll
    for (int i = 0; i < 8; i++) {
      t0[i] = fmaxf(t0[i], NEG * t0[i]);
      t1[i] = fmaxf(t1[i], NEG * t1[i]);
    }
    float p0 = 0.f, p1 = 0.f;
    #pragma unroll
    for (int i = 0; i < 8; i++) { p0 += t0[i] * at[i]; p1 += t1[i] * at[i]; }
    p0 += __shfl_xor(p0, 1, 64);  p1 += __shfl_xor(p1, 1, 64);
    p0 += __shfl_xor(p0, 2, 64);  p1 += __shfl_xor(p1, 2, 64);
    p0 += __shfl_xor(p0, 4, 64);  p1 += __shfl_xor(p1, 4, 64);
    float wv0 = __expf(fminf(p0, 60.f));
    float wv1 = h2v ? __expf(fminf(p1, 60.f)) : 0.f;
    acc += wv0 * xl0;
    acc += wv1 * xl1;
    l += wv0 + wv1;
  }

  f32x8 b8 = *(const f32x8*)(bias + cr);
  f32x8 o = acc * (1.f / (l + 1e-16f)) + b8;
  if (layer1) {
    #pragma unroll
    for (int i = 0; i < 8; i++) o[i] = o[i] > 0.f ? o[i] : (__expf(o[i]) - 1.f);
    uint4 pk;
    pk.x = ((unsigned int)f2bf(o[1]) << 16) | f2bf(o[0]);
    pk.y = ((unsigned int)f2bf(o[3]) << 16) | f2bf(o[2]);
    pk.z = ((unsigned int)f2bf(o[5]) << 16) | f2bf(o[4]);
    pk.w = ((unsigned int)f2bf(o[7]) << 16) | f2bf(o[6]);
    if (!v) pk = (uint4){0u, 0u, 0u, 0u};     // keep h1 pads clean
    *(uint4*)(outb + (size_t)n * PS + pc) = pk;
  } else if (v) {
    float* dst = outf + (size_t)n * HC + cr;
    *(f32x4*)dst       = (f32x4){o[0], o[1], o[2], o[3]};
    *(f32x4*)(dst + 4) = (f32x4){o[4], o[5], o[6], o[7]};
  }
}

// per-channel sum / sumsq over NN rows of padded bf16 h1
__global__ __launch_bounds__(448) void k_bnstats(const unsigned short* __restrict__ h,
                                                 float* stat) {
  int c = threadIdx.x;
  int cp = c + 8 * (c / 56);             // padded index
  int rows_per = (NN + gridDim.x - 1) / gridDim.x;
  int r0 = blockIdx.x * rows_per, r1 = min(NN, r0 + rows_per);
  float s = 0.f, sq = 0.f;
  for (int r = r0; r < r1; r++) {
    unsigned int u = h[(size_t)r * PS + cp];
    float v = __uint_as_float(u << 16);
    s += v; sq += v * v;
  }
  atomicAdd(&stat[c], s);
  atomicAdd(&stat[HC + c], sq);
}

// fold BN into W2: W2s[j][k'] = bf16(sc[k]*W2t[j][k]) (padded K, pads=0),
// bias2[j] = sum_k sh[k]*W2t[j][k]. One 64-thread block per j.
__global__ __launch_bounds__(64) void k_w2fix(const unsigned short* __restrict__ W2t,
                                              const float* __restrict__ stat,
                                              const float* __restrict__ gam,
                                              const float* __restrict__ bet,
                                              unsigned short* __restrict__ W2s,
                                              float* __restrict__ bias2) {
  int j = blockIdx.x;
  int t = threadIdx.x;
  float bacc = 0.f;
  #pragma unroll
  for (int it = 0; it < 7; it++) {
    int k = t + it * 64;
    float w = __uint_as_float((unsigned int)W2t[(size_t)j * HC + k] << 16);
    float mean = stat[k] * (1.f / NN);
    float var  = stat[HC + k] * (1.f / NN) - mean * mean;
    float sc = rsqrtf(var + 1e-5f) * gam[k];
    float sh = bet[k] - mean * sc;
    bacc += sh * w;
    int kp = k + 8 * (k / 56);
    W2s[(size_t)j * PS + kp] = f2bf(sc * w);
  }
  // zero the 64 pad slots
  W2s[(size_t)j * PS + (t >> 3) * 64 + 56 + (t & 7)] = 0;
  #pragma unroll
  for (int m = 32; m >= 1; m >>= 1) bacc += __shfl_xor(bacc, m, 64);
  if (t == 0) bias2[j] = bacc;
}

// LDS-staged bf16 MFMA GEMM: xlr2[NN,1024p] = h1b[NN,512p] @ W2s[896,512p]^T
// + bias2.  BK=64, 128x128 tile, XCD-aligned 1-D grid swizzle.
__global__ __launch_bounds__(256) void k_gemm2(const unsigned short* __restrict__ A,
                                               const unsigned short* __restrict__ Bt,
                                               const float* __restrict__ bias2,
                                               unsigned short* __restrict__ out) {
  __shared__ unsigned short As[128 * 64];
  __shared__ unsigned short Bs[128 * 64];
  int bid = blockIdx.x;
  int g = bid / 56, rem = bid - g * 56;
  int xs = min(8, MT - g * 8);
  int bx = g * 8 + rem % xs;
  int by = rem / xs;
  int t = threadIdx.x;
  int w = t >> 6, lane = t & 63;
  int wm = w >> 1, wn = w & 1;
  int q = lane >> 4, r = lane & 15;
  int m0 = bx * 128;
  int n0 = by * 128;

  const unsigned short *ag[4], *bg[4];
  unsigned short *la[4], *lb[4];
  #pragma unroll
  for (int j = 0; j < 4; j++) {
    int s = t + j * 256;
    int row = s >> 3, part = s & 7;
    int ar = m0 + row; if (ar >= NN) ar = NN - 1;
    ag[j] = A + (size_t)ar * PS + part * 8;
    bg[j] = Bt + (size_t)(n0 + row) * PS + part * 8;
    la[j] = As + s * 8;
    lb[j] = Bs + s * 8;
  }

  f32x4 zero = {0.f, 0.f, 0.f, 0.f};
  f32x4 acc[4][4];
  #pragma unroll
  for (int i = 0; i < 4; i++)
    #pragma unroll
    for (int j = 0; j < 4; j++) acc[i][j] = zero;

  for (int k0 = 0; k0 < PS; k0 += 64) {
    #pragma unroll
    for (int j = 0; j < 4; j++) {
      __builtin_amdgcn_global_load_lds(
          (const __attribute__((address_space(1))) unsigned int*)(ag[j] + k0),
          (__attribute__((address_space(3))) unsigned int*)la[j], 16, 0, 0);
      __builtin_amdgcn_global_load_lds(
          (const __attribute__((address_space(1))) unsigned int*)(bg[j] + k0),
          (__attribute__((address_space(3))) unsigned int*)lb[j], 16, 0, 0);
    }
    __syncthreads();
    #pragma unroll
    for (int kk = 0; kk < 64; kk += 32) {
      bf16x8 af[4], bf[4];
      #pragma unroll
      for (int i = 0; i < 4; i++)
        af[i] = *(const bf16x8*)(As + (wm * 64 + i * 16 + r) * 64 + kk + q * 8);
      #pragma unroll
      for (int j = 0; j < 4; j++)
        bf[j] = *(const bf16x8*)(Bs + (wn * 64 + j * 16 + r) * 64 + kk + q * 8);
      #pragma unroll
      for (int i = 0; i < 4; i++)
        #pragma unroll
        for (int j = 0; j < 4; j++)
          acc[i][j] = __builtin_amdgcn_mfma_f32_16x16x32_bf16(af[i], bf[j], acc[i][j], 0, 0, 0);
    }
    __syncthreads();
  }

  #pragma unroll
  for (int j = 0; j < 4; j++) {
    int col = n0 + wn * 64 + j * 16 + r;
    int cp = col + 8 * (col / 56);       // padded output column
    float bs = bias2[col];
    #pragma unroll
    for (int i = 0; i < 4; i++) {
      int row_base = m0 + wm * 64 + i * 16 + q * 4;
      #pragma unroll
      for (int reg = 0; reg < 4; reg++) {
        int row = row_base + reg;
        if (row < NN) out[(size_t)row * PSS + cp] = f2bf(acc[i][j][reg] + bs);
      }
    }
  }
}

// segment-sum pool over sorted batch; also counts rows per graph (thread 0)
__global__ __launch_bounds__(448) void k_pool(const float* __restrict__ h2,
                                              const int* __restrict__ batch,
                                              float* pooled, int* cnt) {
  int c = threadIdx.x;
  int rows_per = (NN + gridDim.x - 1) / gridDim.x;
  int r0 = blockIdx.x * rows_per, r1 = min(NN, r0 + rows_per);
  if (r0 >= r1) return;
  float loc = 0.f;
  int rc = 0;
  int gcur = batch[r0];
  for (int r = r0; r < r1; r++) {
    int g = batch[r];
    if (g != gcur) {
      atomicAdd(&pooled[gcur * HC + c], loc);
      if (c == 0) atomicAdd(&cnt[gcur], rc);
      loc = 0.f; rc = 0; gcur = g;
    }
    loc += h2[(size_t)r * HC + c];
    rc++;
  }
  atomicAdd(&pooled[gcur * HC + c], loc);
  if (c == 0) atomicAdd(&cnt[gcur], rc);
}

// pooled mean -> BN over 32 graphs -> logits -> log_softmax (single block)
__global__ __launch_bounds__(448) void k_final(const float* __restrict__ pooled_sum,
                                               const int* __restrict__ cnt,
                                               const float* __restrict__ gam,
                                               const float* __restrict__ bet,
                                               const float* __restrict__ Wlin,
                                               const float* __restrict__ blin,
                                               float* __restrict__ out) {
  __shared__ float P[GG * HC];
  __shared__ float L[GG * 18];
  __shared__ float red[GG];
  int c = threadIdx.x;
  float s = 0.f, sq = 0.f;
  for (int g = 0; g < GG; g++) {
    float v = pooled_sum[g * HC + c] / fmaxf((float)cnt[g], 1.f);
    P[g * HC + c] = v; s += v; sq += v * v;
  }
  float mean = s * (1.f / GG);
  float var  = sq * (1.f / GG) - mean * mean;
  float sc = rsqrtf(var + 1e-5f) * gam[c];
  float sh = bet[c] - mean * sc;
  for (int g = 0; g < GG; g++) P[g * HC + c] = P[g * HC + c] * sc + sh;
  __syncthreads();
  for (int o = c; o < GG * 18; o += HC) {
    int g = o / 18, j = o - g * 18;
    float acc = blin[j];
    for (int k = 0; k < HC; k++) acc += P[g * HC + k] * Wlin[k * 18 + j];
    L[o] = acc;
  }
  __syncthreads();
  if (c < GG) {
    float mx = -3.4e38f;
    for (int j = 0; j < 18; j++) mx = fmaxf(mx, L[c * 18 + j]);
    float se = 0.f;
    for (int j = 0; j < 18; j++) se += __expf(L[c * 18 + j] - mx);
    red[c] = mx + logf(se);
  }
  __syncthreads();
  for (int o = c; o < GG * 18; o += HC) out[o] = L[o] - red[o / 18];
}

extern "C" void kernel_launch(void* const* d_in, const int* in_sizes, int n_in,
                              void* d_out, int out_size, void* d_ws, size_t ws_size,
                              hipStream_t stream) {
  (void)in_sizes; (void)n_in; (void)out_size; (void)ws_size;
  const float* x     = (const float*)d_in[0];
  const int*   ei    = (const int*)d_in[1];
  const float* ea    = (const float*)d_in[2];
  const int*   batch = (const int*)d_in[3];
  const float* Wl1   = (const float*)d_in[4];
  const float* Wr1   = (const float*)d_in[5];
  const float* We1   = (const float*)d_in[6];
  const float* att1  = (const float*)d_in[7];
  const float* bias1 = (const float*)d_in[8];
  const float* Wl2   = (const float*)d_in[9];
  const float* Wr2   = (const float*)d_in[10];
  const float* We2   = (const float*)d_in[11];
  const float* att2  = (const float*)d_in[12];
  const float* bias2in = (const float*)d_in[13];
  const float* gam   = (const float*)d_in[14];
  const float* bet   = (const float*)d_in[15];
  const float* Wlin  = (const float*)d_in[16];
  const float* blin  = (const float*)d_in[17];
  float* out = (float*)d_out;
  const int* srcp = ei;
  const int* dstp = ei + EE;

  char* ws = (char*)d_ws;
  size_t off = 0;
  auto alloc = [&](size_t bytes) -> char* {
    char* p = ws + off;
    off = (off + bytes + 255) & ~(size_t)255;
    return p;
  };
  // zero-region: deg | bnstat | pooled | cnt (contiguous, one memset)
  int*   deg     = (int*)  alloc(NN * 4);
  float* bnstat  = (float*)alloc(HC * 2 * 4);
  float* pooled  = (float*)alloc(GG * HC * 4 + GG * 4);
  int*   cnt     = (int*)(pooled + GG * HC);
  size_t zlen    = (size_t)((char*)(cnt + GG) - (char*)deg);

  int*   offs    = (int*)  alloc((NN + 1) * 4);
  int*   cursor  = (int*)  alloc(NN * 4);
  int*   csr_src = (int*)  alloc((size_t)EN * 4);
  float* csr_ea  = (float*)alloc((size_t)EN * EAS * 4);
  unsigned short* xlr = (unsigned short*)alloc((size_t)NN * PSS * 2); // padded bf16
  unsigned short* h1b = (unsigned short*)alloc((size_t)NN * PS * 2);  // L1 out, padded bf16
  float* h1f     = (float*)alloc((size_t)NN * HC * 4);                // L2 out, fp32
  unsigned short* xb  = (unsigned short*)alloc((size_t)NN * DINN * 2);
  unsigned short* W1t = (unsigned short*)alloc((size_t)SS * DINN * 2);
  unsigned short* W2t = (unsigned short*)alloc((size_t)SS * HC * 2);
  unsigned short* W2s = (unsigned short*)alloc((size_t)SS * PS * 2);
  float* bias2   = (float*)alloc(SS * 4);

  // ---- preprocessing: CSR by dst ----
  hipMemsetAsync(deg, 0, zlen, stream);
  k_deg<<<(EE + 255) / 256, 256, 0, stream>>>(dstp, deg);
  k_scan<<<1, 1024, 0, stream>>>(deg, offs, cursor);
  k_scatter<<<(EE + 255) / 256, 256, 0, stream>>>(srcp, dstp, ea, cursor, csr_src, csr_ea);
  k_aux<<<(NN + XCN + W1N + W2N + 255) / 256, 256, 0, stream>>>(
      offs, csr_src, csr_ea, x, xb, Wl1, Wr1, W1t, Wl2, Wr2, W2t);

  // ---- layer 1 ----
  dim3 g1((NN + 63) / 64, SS / 64);
  k_gemm1<<<g1, 256, 0, stream>>>(xb, W1t, xlr);
  k_attn<<<(NN + 3) / 4, 256, 0, stream>>>(xlr, offs, csr_src, csr_ea,
                                           We1, att1, bias1, h1b, h1f, 1);
  // ---- BN (stats + fold into W2) ----
  k_bnstats<<<256, HC, 0, stream>>>(h1b, bnstat);
  k_w2fix<<<SS, 64, 0, stream>>>(W2t, bnstat, gam, bet, W2s, bias2);

  // ---- layer 2 ----
  k_gemm2<<<MT * NT, 256, 0, stream>>>(h1b, W2s, bias2, xlr);
  k_attn<<<(NN + 3) / 4, 256, 0, stream>>>(xlr, offs, csr_src, csr_ea,
                                           We2, att2, bias2in, h1b, h1f, 0);

  // ---- pool + final ----
  k_pool<<<640, HC, 0, stream>>>(h1f, batch, pooled, cnt);
  k_final<<<1, HC, 0, stream>>>(pooled, cnt, gam, bet, Wlin, blin, out);
}